// Round 4
// baseline (1877.298 us; speedup 1.0000x reference)
//
#include <hip/hip_runtime.h>
#include <cstddef>

// Problem constants
#define N_NODES 50000
#define N_EDGES 800000
#define IN_DIM  128
#define EMB     32
#define ED      8
#define NLAYERS 4
#define NB      64
#define OUTD    10
#define EPS_BN  1e-5f

#define EDGE_GRID 3125   // 800000/256 exact
#define NODE_GRID 196    // ceil(50000/256)
#define AGGR_GRID 6250   // 50000/8
#define ELEM_GRID 6250   // 1600000/256

// ---------------- helpers ----------------

__device__ __forceinline__ unsigned short f2bf(float x) {
  union { float f; unsigned u; } v; v.f = x;
  unsigned b = v.u + 0x7FFFu + ((v.u >> 16) & 1u);
  return (unsigned short)(b >> 16);
}
__device__ __forceinline__ float bf2f(unsigned short s) {
  union { unsigned u; float f; } v; v.u = ((unsigned)s) << 16;
  return v.f;
}

// acc[c] += v.{x,y,z,w} * w[k..k+3][c]; wk wave-uniform -> scalar loads + v_fmac.
__device__ __forceinline__ void mac_f4(float acc[EMB], const float4 v, const float* __restrict__ wk) {
#pragma unroll
  for (int c = 0; c < EMB; ++c) acc[c] = fmaf(v.x, wk[c], acc[c]);
#pragma unroll
  for (int c = 0; c < EMB; ++c) acc[c] = fmaf(v.y, wk[EMB + c], acc[c]);
#pragma unroll
  for (int c = 0; c < EMB; ++c) acc[c] = fmaf(v.z, wk[2*EMB + c], acc[c]);
#pragma unroll
  for (int c = 0; c < EMB; ++c) acc[c] = fmaf(v.w, wk[3*EMB + c], acc[c]);
}

// Block reduce (sum[32], sumsq[32]) -> partial[blockIdx*64 + {0..63}]. No atomics.
__device__ __forceinline__ void block_partial(const float ts[EMB], const float tss[EMB],
                                              float* __restrict__ partial) {
  __shared__ float sred[256];
  const int lane = threadIdx.x & 63;
  const int wid  = threadIdx.x >> 6;
#pragma unroll
  for (int c = 0; c < EMB; ++c) {
    float a = ts[c];
    float q = tss[c];
#pragma unroll
    for (int o = 32; o > 0; o >>= 1) {
      a += __shfl_down(a, o, 64);
      q += __shfl_down(q, o, 64);
    }
    if (lane == 0) { sred[wid*64 + c] = a; sred[wid*64 + EMB + c] = q; }
  }
  __syncthreads();
  if (threadIdx.x < 64) {
    partial[(size_t)blockIdx.x*64 + threadIdx.x] =
        sred[threadIdx.x] + sred[64 + threadIdx.x] +
        sred[128 + threadIdx.x] + sred[192 + threadIdx.x];
  }
}

// ---------------- kernels ----------------

// h = x @ lin_in_w + lin_in_b
__global__ __launch_bounds__(256) void k_lin_in(
    const float* __restrict__ x, const float* __restrict__ w, const float* __restrict__ b,
    float* __restrict__ h)
{
  const int n = blockIdx.x*256 + threadIdx.x;
  if (n >= N_NODES) return;
  float acc[EMB];
#pragma unroll
  for (int c = 0; c < EMB; ++c) acc[c] = b[c];
  const float4* xp = (const float4*)(x + (size_t)n*IN_DIM);
#pragma unroll 4
  for (int q = 0; q < IN_DIM/4; ++q) mac_f4(acc, xp[q], w + q*4*EMB);
  float4* hp = (float4*)(h + (size_t)n*EMB);
#pragma unroll
  for (int q = 0; q < 8; ++q) {
    float4 o; o.x = acc[4*q]; o.y = acc[4*q+1]; o.z = acc[4*q+2]; o.w = acc[4*q+3];
    hp[q] = o;
  }
}

// p[n] = h[n] @ W1[0:32], q[n] = h[n] @ W1[32:64]
__global__ __launch_bounds__(256) void k_pq(
    const float* __restrict__ h, const float* __restrict__ w1,
    float* __restrict__ p, float* __restrict__ q)
{
  const int n = blockIdx.x*256 + threadIdx.x;
  if (n >= N_NODES) return;
  float ap[EMB], aq[EMB];
#pragma unroll
  for (int c = 0; c < EMB; ++c) { ap[c] = 0.f; aq[c] = 0.f; }
  const float4* hp = (const float4*)(h + (size_t)n*EMB);
#pragma unroll
  for (int q8 = 0; q8 < 8; ++q8) {
    const float4 v = hp[q8];
    mac_f4(ap, v, w1 + q8*4*EMB);
    mac_f4(aq, v, w1 + (EMB + q8*4)*EMB);
  }
  float4* pp = (float4*)(p + (size_t)n*EMB);
  float4* qp = (float4*)(q + (size_t)n*EMB);
#pragma unroll
  for (int q8 = 0; q8 < 8; ++q8) {
    float4 o1; o1.x = ap[4*q8]; o1.y = ap[4*q8+1]; o1.z = ap[4*q8+2]; o1.w = ap[4*q8+3];
    float4 o2; o2.x = aq[4*q8]; o2.y = aq[4*q8+1]; o2.z = aq[4*q8+2]; o2.w = aq[4*q8+3];
    pp[q8] = o1; qp[q8] = o2;
  }
}

// ---- CSR build ----
__global__ __launch_bounds__(256) void k_hist(const int* __restrict__ ei, int* __restrict__ cnt) {
  const int e = blockIdx.x*256 + threadIdx.x;
  if (e < N_EDGES) atomicAdd(&cnt[ei[N_EDGES + e]], 1);
}

__global__ __launch_bounds__(1024) void k_scan(const int* __restrict__ cnt, int* __restrict__ row_ptr) {
  __shared__ int part[1024];
  const int t = threadIdx.x;
  const int CH = (N_NODES + 1023) / 1024;  // 49
  const int lo = t*CH, hi = min(lo + CH, N_NODES);
  int s = 0;
  for (int i = lo; i < hi; ++i) s += cnt[i];
  part[t] = s;
  __syncthreads();
  for (int o = 1; o < 1024; o <<= 1) {
    int v = (t >= o) ? part[t - o] : 0;
    __syncthreads();
    part[t] += v;
    __syncthreads();
  }
  int run = (t == 0) ? 0 : part[t-1];
  for (int i = lo; i < hi; ++i) { row_ptr[i] = run; run += cnt[i]; }
  if (t == 0) row_ptr[N_NODES] = N_EDGES;
}

__global__ __launch_bounds__(256) void k_place(const int* __restrict__ ei,
                                               const int* __restrict__ row_ptr,
                                               int* __restrict__ cnt, int* __restrict__ perm) {
  const int e = blockIdx.x*256 + threadIdx.x;
  if (e >= N_EDGES) return;
  const int d = ei[N_EDGES + e];
  const int pos = row_ptr[d] + atomicAdd(&cnt[d], 1);
  perm[pos] = e;
}

// Gather edge data into CSR position order (ONE random-read pass per call).
__global__ __launch_bounds__(256) void k_permute(
    const int* __restrict__ perm, const int* __restrict__ ei, const float* __restrict__ ea,
    int* __restrict__ src_perm, int* __restrict__ dst_perm, float* __restrict__ ea_perm)
{
  const int i = blockIdx.x*256 + threadIdx.x;
  const int e = perm[i];
  src_perm[i] = ei[e];
  dst_perm[i] = ei[N_EDGES + e];
  const float4* src4 = (const float4*)(ea + (size_t)e*ED);
  float4* d4 = (float4*)(ea_perm + (size_t)i*ED);
  d4[0] = src4[0];
  d4[1] = src4[1];
}

// y1[i] = b1 + p[dst_perm[i]] + q[src_perm[i]] + ea_perm[i] @ w1b; store bf16 [E][32]; fused stats.
__global__ __launch_bounds__(256) void k_msg1(
    const float* __restrict__ p, const float* __restrict__ q,
    const int* __restrict__ src_perm, const int* __restrict__ dst_perm,
    const float* __restrict__ ea_perm,
    const float* __restrict__ w1b, const float* __restrict__ b1,
    unsigned short* __restrict__ y, float* __restrict__ partial)
{
  const int i = blockIdx.x*256 + threadIdx.x;
  const int dst = dst_perm[i];
  const int src = src_perm[i];
  float acc[EMB];
  const float4* pd = (const float4*)(p + (size_t)dst*EMB);
  const float4* qs = (const float4*)(q + (size_t)src*EMB);
#pragma unroll
  for (int q8 = 0; q8 < 8; ++q8) {
    const float4 a = pd[q8];
    const float4 b = qs[q8];
    acc[4*q8+0] = b1[4*q8+0] + a.x + b.x;
    acc[4*q8+1] = b1[4*q8+1] + a.y + b.y;
    acc[4*q8+2] = b1[4*q8+2] + a.z + b.z;
    acc[4*q8+3] = b1[4*q8+3] + a.w + b.w;
  }
  const float4* ep = (const float4*)(ea_perm + (size_t)i*ED);
  mac_f4(acc, ep[0], w1b);
  mac_f4(acc, ep[1], w1b + 4*EMB);

  unsigned short us[EMB];
#pragma unroll
  for (int c = 0; c < EMB; ++c) us[c] = f2bf(acc[c]);
  unsigned int u[16];
#pragma unroll
  for (int j = 0; j < 16; ++j)
    u[j] = (unsigned)us[2*j] | ((unsigned)us[2*j+1] << 16);
  uint4* dp = (uint4*)(y + (size_t)i*EMB);
#pragma unroll
  for (int j = 0; j < 4; ++j) {
    uint4 o; o.x = u[4*j]; o.y = u[4*j+1]; o.z = u[4*j+2]; o.w = u[4*j+3];
    dp[j] = o;
  }
  float ts[EMB], tss[EMB];
#pragma unroll
  for (int c = 0; c < EMB; ++c) {
    const float v = bf2f(us[c]);
    ts[c] = v;
    tss[c] = v*v;
  }
  block_partial(ts, tss, partial);
}

// BN finalize from partials, parallel (1024 thr, 16-way row split + LDS tree).
__global__ __launch_bounds__(1024) void k_bnfin(
    const float* __restrict__ partial, int nblocks,
    const float* __restrict__ g, const float* __restrict__ be,
    float* __restrict__ coef, float inv_count)
{
  __shared__ float sred[1024];
  __shared__ float tot[64];
  const int c = threadIdx.x & 63;
  const int r = threadIdx.x >> 6;
  float s = 0.f;
  for (int b = r; b < nblocks; b += 16) s += partial[(size_t)b*64 + c];
  sred[threadIdx.x] = s;
  __syncthreads();
  if (threadIdx.x < 64) {
    float t = 0.f;
#pragma unroll
    for (int m = 0; m < 16; ++m) t += sred[m*64 + threadIdx.x];
    tot[threadIdx.x] = t;
  }
  __syncthreads();
  if (threadIdx.x < EMB) {
    const float mu  = tot[threadIdx.x] * inv_count;
    const float var = tot[EMB + threadIdx.x] * inv_count - mu*mu;
    const float a = g[threadIdx.x] * rsqrtf(var + EPS_BN);
    coef[threadIdx.x] = a;
    coef[EMB + threadIdx.x] = fmaf(-mu, a, be[threadIdx.x]);
  }
}

// Streaming: read y1 row (bf16), BN1+ReLU, @ w2 + b2, overwrite same row with y2 (bf16); stats.
__global__ __launch_bounds__(256) void k_msg2(
    unsigned short* __restrict__ y,
    const float* __restrict__ coef1,
    const float* __restrict__ w2, const float* __restrict__ b2,
    float* __restrict__ partial)
{
  const int i = blockIdx.x*256 + threadIdx.x;
  uint4* rowp = (uint4*)(y + (size_t)i*EMB);
  uint4 r0 = rowp[0], r1 = rowp[1], r2 = rowp[2], r3 = rowp[3];
  unsigned int uin[16] = {r0.x,r0.y,r0.z,r0.w, r1.x,r1.y,r1.z,r1.w,
                          r2.x,r2.y,r2.z,r2.w, r3.x,r3.y,r3.z,r3.w};
  float acc[EMB];
#pragma unroll
  for (int c = 0; c < EMB; ++c) acc[c] = b2[c];
#pragma unroll
  for (int j = 0; j < 16; ++j) {
    const float v0 = bf2f((unsigned short)(uin[j] & 0xFFFFu));
    const float v1 = bf2f((unsigned short)(uin[j] >> 16));
    const int k0 = 2*j, k1 = 2*j + 1;
    const float m0 = fmaxf(fmaf(coef1[k0], v0, coef1[EMB + k0]), 0.f);
    const float m1 = fmaxf(fmaf(coef1[k1], v1, coef1[EMB + k1]), 0.f);
    const float* wk0 = w2 + k0*EMB;
    const float* wk1 = w2 + k1*EMB;
#pragma unroll
    for (int c = 0; c < EMB; ++c) acc[c] = fmaf(m0, wk0[c], acc[c]);
#pragma unroll
    for (int c = 0; c < EMB; ++c) acc[c] = fmaf(m1, wk1[c], acc[c]);
  }
  unsigned short us[EMB];
#pragma unroll
  for (int c = 0; c < EMB; ++c) us[c] = f2bf(acc[c]);
  unsigned int u[16];
#pragma unroll
  for (int j = 0; j < 16; ++j)
    u[j] = (unsigned)us[2*j] | ((unsigned)us[2*j+1] << 16);
#pragma unroll
  for (int j = 0; j < 4; ++j) {
    uint4 o; o.x = u[4*j]; o.y = u[4*j+1]; o.z = u[4*j+2]; o.w = u[4*j+3];
    rowp[j] = o;
  }
  float ts[EMB], tss[EMB];
#pragma unroll
  for (int c = 0; c < EMB; ++c) {
    const float v = bf2f(us[c]);
    ts[c] = v;
    tss[c] = v*v;
  }
  block_partial(ts, tss, partial);
}

// CSR gather, now fully sequential: aggr[n][c] = sum_{i in [lo,hi)} relu(bn2(y[i][c]))
__global__ __launch_bounds__(256) void k_aggr(
    const unsigned short* __restrict__ y, const int* __restrict__ row_ptr,
    const float* __restrict__ coef2, float* __restrict__ aggr)
{
  const int g = threadIdx.x >> 5;
  const int c = threadIdx.x & 31;
  const int n = blockIdx.x*8 + g;
  if (n >= N_NODES) return;
  const float a = coef2[c], b = coef2[EMB + c];
  const int lo = row_ptr[n], hi = row_ptr[n+1];
  float s = 0.f;
  for (int i = lo; i < hi; ++i) {
    const float v = bf2f(y[(size_t)i*EMB + c]);
    s += fmaxf(fmaf(a, v, b), 0.f);
  }
  aggr[(size_t)n*EMB + c] = s;
}

// z1 = concat(h, aggr) @ uw1 + b, written IN PLACE into aggr. stats.
__global__ __launch_bounds__(256) void k_upd1(
    const float* __restrict__ h, float* __restrict__ aggr,
    const float* __restrict__ w, const float* __restrict__ b,
    float* __restrict__ partial)
{
  const int n = blockIdx.x*256 + threadIdx.x;
  float acc[EMB];
#pragma unroll
  for (int c = 0; c < EMB; ++c) acc[c] = 0.f;
  if (n < N_NODES) {
#pragma unroll
    for (int c = 0; c < EMB; ++c) acc[c] = b[c];
    const float4* hp = (const float4*)(h + (size_t)n*EMB);
    const float4* ap = (const float4*)(aggr + (size_t)n*EMB);
#pragma unroll
    for (int q8 = 0; q8 < 8; ++q8) mac_f4(acc, hp[q8], w + q8*4*EMB);
#pragma unroll
    for (int q8 = 0; q8 < 8; ++q8) mac_f4(acc, ap[q8], w + (EMB + q8*4)*EMB);
    float4* zp = (float4*)(aggr + (size_t)n*EMB);
#pragma unroll
    for (int q8 = 0; q8 < 8; ++q8) {
      float4 o; o.x = acc[4*q8]; o.y = acc[4*q8+1]; o.z = acc[4*q8+2]; o.w = acc[4*q8+3];
      zp[q8] = o;
    }
  }
  float ts[EMB], tss[EMB];
#pragma unroll
  for (int c = 0; c < EMB; ++c) { ts[c] = acc[c]; tss[c] = acc[c]*acc[c]; }
  block_partial(ts, tss, partial);
}

// z2 = relu(bn(z1)) @ uw2 + b, in place. stats.
__global__ __launch_bounds__(256) void k_upd2(
    float* __restrict__ z, const float* __restrict__ coef1,
    const float* __restrict__ w, const float* __restrict__ b,
    float* __restrict__ partial)
{
  const int n = blockIdx.x*256 + threadIdx.x;
  float acc[EMB];
#pragma unroll
  for (int c = 0; c < EMB; ++c) acc[c] = 0.f;
  if (n < N_NODES) {
#pragma unroll
    for (int c = 0; c < EMB; ++c) acc[c] = b[c];
    const float4* zp = (const float4*)(z + (size_t)n*EMB);
#pragma unroll
    for (int q8 = 0; q8 < 8; ++q8) {
      const float4 v = zp[q8];
      float mv[4] = {v.x, v.y, v.z, v.w};
#pragma unroll
      for (int j = 0; j < 4; ++j) {
        const int k = 4*q8 + j;
        const float m = fmaxf(fmaf(coef1[k], mv[j], coef1[EMB + k]), 0.f);
        const float* wk = w + k*EMB;
#pragma unroll
        for (int c = 0; c < EMB; ++c) acc[c] = fmaf(m, wk[c], acc[c]);
      }
    }
    float4* op = (float4*)(z + (size_t)n*EMB);
#pragma unroll
    for (int q8 = 0; q8 < 8; ++q8) {
      float4 o; o.x = acc[4*q8]; o.y = acc[4*q8+1]; o.z = acc[4*q8+2]; o.w = acc[4*q8+3];
      op[q8] = o;
    }
  }
  float ts[EMB], tss[EMB];
#pragma unroll
  for (int c = 0; c < EMB; ++c) { ts[c] = acc[c]; tss[c] = acc[c]*acc[c]; }
  block_partial(ts, tss, partial);
}

// h += relu(bn(z2))
__global__ __launch_bounds__(256) void k_resid(
    float* __restrict__ h, const float* __restrict__ z, const float* __restrict__ coef)
{
  const int t = blockIdx.x*256 + threadIdx.x;
  const int c = t & (EMB-1);
  const float v = fmaf(coef[c], z[t], coef[EMB + c]);
  h[t] += fmaxf(v, 0.f);
}

// per-graph mean pool + final linear
__global__ void k_pool(const float* __restrict__ h, const int* __restrict__ batch,
                       const float* __restrict__ pw, const float* __restrict__ pb,
                       float* __restrict__ out)
{
  __shared__ float sred[256];
  __shared__ float hg[EMB];
  const int b = blockIdx.x;
  int lo = 0, hi = N_NODES;
  while (lo < hi) { int m = (lo + hi) >> 1; if (batch[m] < b) lo = m + 1; else hi = m; }
  const int start = lo;
  hi = N_NODES;
  while (lo < hi) { int m = (lo + hi) >> 1; if (batch[m] < b + 1) lo = m + 1; else hi = m; }
  const int end = lo;

  const int c = threadIdx.x & (EMB-1);
  const int r = threadIdx.x >> 5;
  float s = 0.f;
  for (int n = start + r; n < end; n += 8) s += h[(size_t)n*EMB + c];
  sred[threadIdx.x] = s;
  __syncthreads();
  if (threadIdx.x < EMB) {
    float tot = 0.f;
#pragma unroll
    for (int r2 = 0; r2 < 8; ++r2) tot += sred[r2*EMB + threadIdx.x];
    const float cnt = (float)(end - start);
    hg[threadIdx.x] = tot / fmaxf(cnt, 1.f);
  }
  __syncthreads();
  if (threadIdx.x < OUTD) {
    float acc = pb[threadIdx.x];
#pragma unroll
    for (int cc = 0; cc < EMB; ++cc) acc = fmaf(hg[cc], pw[cc*OUTD + threadIdx.x], acc);
    out[b*OUTD + threadIdx.x] = acc;
  }
}

// ---------------- host ----------------

extern "C" void kernel_launch(void* const* d_in, const int* in_sizes, int n_in,
                              void* d_out, int out_size, void* d_ws, size_t ws_size,
                              hipStream_t stream) {
  const float* x        = (const float*)d_in[0];
  const int*   ei       = (const int*)  d_in[1];
  const float* ea       = (const float*)d_in[2];
  const int*   batch    = (const int*)  d_in[3];
  const float* lin_in_w = (const float*)d_in[4];
  const float* lin_in_b = (const float*)d_in[5];
  const float* msg_w1   = (const float*)d_in[6];
  const float* msg_b1   = (const float*)d_in[7];
  const float* msg_g1   = (const float*)d_in[8];
  const float* msg_be1  = (const float*)d_in[9];
  const float* msg_w2   = (const float*)d_in[10];
  const float* msg_b2   = (const float*)d_in[11];
  const float* msg_g2   = (const float*)d_in[12];
  const float* msg_be2  = (const float*)d_in[13];
  const float* upd_w1   = (const float*)d_in[14];
  const float* upd_b1   = (const float*)d_in[15];
  const float* upd_g1   = (const float*)d_in[16];
  const float* upd_be1  = (const float*)d_in[17];
  const float* upd_w2   = (const float*)d_in[18];
  const float* upd_b2   = (const float*)d_in[19];
  const float* upd_g2   = (const float*)d_in[20];
  const float* upd_be2  = (const float*)d_in[21];
  const float* pred_w   = (const float*)d_in[22];
  const float* pred_b   = (const float*)d_in[23];
  float* out = (float*)d_out;

  // Workspace layout (~113 MB)
  char* wsb = (char*)d_ws;
  unsigned short* y = (unsigned short*)wsb;             // E*32 bf16 = 51.2 MB (y1 then y2 in place)
  float* ea_perm = (float*)(wsb + (size_t)N_EDGES*EMB*2);  // E*8 f32 = 25.6 MB
  float* h       = ea_perm + (size_t)N_EDGES*ED;
  float* p       = h    + (size_t)N_NODES*EMB;
  float* q       = p    + (size_t)N_NODES*EMB;
  float* aggr    = q    + (size_t)N_NODES*EMB;          // also z1/z2 in place
  float* partial = aggr + (size_t)N_NODES*EMB;          // 3200 rows x 64
  float* coef    = partial + (size_t)3200*64;           // 16 stages x 64
  int*   perm    = (int*)(coef + 16*64);
  int*   src_perm= perm + N_EDGES;
  int*   dst_perm= src_perm + N_EDGES;
  int*   cnt     = dst_perm + N_EDGES;
  int*   row_ptr = cnt + N_NODES;
  const size_t need = ((size_t)((char*)(row_ptr + N_NODES + 1) - wsb));
  if (ws_size < need) return;

  const float invE = 1.0f / (float)N_EDGES;
  const float invN = 1.0f / (float)N_NODES;

  // input projection + CSR build + edge-data permute (once per call)
  k_lin_in<<<NODE_GRID, 256, 0, stream>>>(x, lin_in_w, lin_in_b, h);
  hipMemsetAsync(cnt, 0, N_NODES*sizeof(int), stream);
  k_hist<<<EDGE_GRID, 256, 0, stream>>>(ei, cnt);
  k_scan<<<1, 1024, 0, stream>>>(cnt, row_ptr);
  hipMemsetAsync(cnt, 0, N_NODES*sizeof(int), stream);
  k_place<<<EDGE_GRID, 256, 0, stream>>>(ei, row_ptr, cnt, perm);
  k_permute<<<EDGE_GRID, 256, 0, stream>>>(perm, ei, ea, src_perm, dst_perm, ea_perm);

  for (int l = 0; l < NLAYERS; ++l) {
    const int st = l*4;
    const float* w1  = msg_w1 + (size_t)l*(2*EMB+ED)*EMB;
    const float* w1b = w1 + (size_t)2*EMB*EMB;  // ea rows
    const float* w2  = msg_w2 + (size_t)l*EMB*EMB;
    const float* uw1 = upd_w1 + (size_t)l*(2*EMB)*EMB;
    const float* uw2 = upd_w2 + (size_t)l*EMB*EMB;

    k_pq<<<NODE_GRID, 256, 0, stream>>>(h, w1, p, q);
    k_msg1<<<EDGE_GRID, 256, 0, stream>>>(p, q, src_perm, dst_perm, ea_perm,
                                          w1b, msg_b1 + l*EMB, y, partial);
    k_bnfin<<<1, 1024, 0, stream>>>(partial, EDGE_GRID, msg_g1 + l*EMB, msg_be1 + l*EMB,
                                    coef + st*64, invE);
    k_msg2<<<EDGE_GRID, 256, 0, stream>>>(y, coef + st*64, w2, msg_b2 + l*EMB, partial);
    k_bnfin<<<1, 1024, 0, stream>>>(partial, EDGE_GRID, msg_g2 + l*EMB, msg_be2 + l*EMB,
                                    coef + (st+1)*64, invE);
    k_aggr<<<AGGR_GRID, 256, 0, stream>>>(y, row_ptr, coef + (st+1)*64, aggr);
    k_upd1<<<NODE_GRID, 256, 0, stream>>>(h, aggr, uw1, upd_b1 + l*EMB, partial);
    k_bnfin<<<1, 1024, 0, stream>>>(partial, NODE_GRID, upd_g1 + l*EMB, upd_be1 + l*EMB,
                                    coef + (st+2)*64, invN);
    k_upd2<<<NODE_GRID, 256, 0, stream>>>(aggr, coef + (st+2)*64, uw2, upd_b2 + l*EMB, partial);
    k_bnfin<<<1, 1024, 0, stream>>>(partial, NODE_GRID, upd_g2 + l*EMB, upd_be2 + l*EMB,
                                    coef + (st+3)*64, invN);
    k_resid<<<ELEM_GRID, 256, 0, stream>>>(h, aggr, coef + (st+3)*64);
  }

  k_pool<<<NB, 256, 0, stream>>>(h, batch, pred_w, pred_b, out);
}

// Round 5
// 1283.310 us; speedup vs baseline: 1.4629x; 1.4629x over previous
//
#include <hip/hip_runtime.h>
#include <cstddef>

// Problem constants
#define N_NODES 50000
#define N_EDGES 800000
#define IN_DIM  128
#define EMB     32
#define ED      8
#define NLAYERS 4
#define NB      64
#define OUTD    10
#define EPS_BN  1e-5f

#define EDGE_GRID 3125   // 800000/256 exact
#define NODE_GRID 196    // ceil(50000/256)
#define AGGR_GRID 6250   // 50000/8
#define ELEM_GRID 6250   // 1600000/256

// msg1: 4 edges/thread
#define MSG1_EPT  4
#define MSG1_GRID 782    // ceil(800000/1024)

// msg2 (MFMA): 16-edge tiles, 16 tiles/wave, 4 waves/block -> 1024 edges/block
#define NT16       50000 // 800000/16
#define MSG2_TPW   16
#define MSG2_GRID  782   // ceil(50000/64)

typedef short bf16x8 __attribute__((ext_vector_type(8)));
typedef float f32x4  __attribute__((ext_vector_type(4)));

// ---------------- helpers ----------------

__device__ __forceinline__ unsigned short f2bf(float x) {
  union { float f; unsigned u; } v; v.f = x;
  unsigned b = v.u + 0x7FFFu + ((v.u >> 16) & 1u);
  return (unsigned short)(b >> 16);
}
__device__ __forceinline__ float bf2f(unsigned short s) {
  union { unsigned u; float f; } v; v.u = ((unsigned)s) << 16;
  return v.f;
}

__device__ __forceinline__ void mac_f4(float acc[EMB], const float4 v, const float* __restrict__ wk) {
#pragma unroll
  for (int c = 0; c < EMB; ++c) acc[c] = fmaf(v.x, wk[c], acc[c]);
#pragma unroll
  for (int c = 0; c < EMB; ++c) acc[c] = fmaf(v.y, wk[EMB + c], acc[c]);
#pragma unroll
  for (int c = 0; c < EMB; ++c) acc[c] = fmaf(v.z, wk[2*EMB + c], acc[c]);
#pragma unroll
  for (int c = 0; c < EMB; ++c) acc[c] = fmaf(v.w, wk[3*EMB + c], acc[c]);
}

// Block reduce (sum[32], sumsq[32]) -> partial[blockIdx*64 + {0..63}]. No atomics.
__device__ __forceinline__ void block_partial(const float ts[EMB], const float tss[EMB],
                                              float* __restrict__ partial) {
  __shared__ float sred[256];
  const int lane = threadIdx.x & 63;
  const int wid  = threadIdx.x >> 6;
#pragma unroll
  for (int c = 0; c < EMB; ++c) {
    float a = ts[c];
    float q = tss[c];
#pragma unroll
    for (int o = 32; o > 0; o >>= 1) {
      a += __shfl_down(a, o, 64);
      q += __shfl_down(q, o, 64);
    }
    if (lane == 0) { sred[wid*64 + c] = a; sred[wid*64 + EMB + c] = q; }
  }
  __syncthreads();
  if (threadIdx.x < 64) {
    partial[(size_t)blockIdx.x*64 + threadIdx.x] =
        sred[threadIdx.x] + sred[64 + threadIdx.x] +
        sred[128 + threadIdx.x] + sred[192 + threadIdx.x];
  }
}

// ---------------- kernels ----------------

// h = x @ lin_in_w + lin_in_b
__global__ __launch_bounds__(256) void k_lin_in(
    const float* __restrict__ x, const float* __restrict__ w, const float* __restrict__ b,
    float* __restrict__ h)
{
  const int n = blockIdx.x*256 + threadIdx.x;
  if (n >= N_NODES) return;
  float acc[EMB];
#pragma unroll
  for (int c = 0; c < EMB; ++c) acc[c] = b[c];
  const float4* xp = (const float4*)(x + (size_t)n*IN_DIM);
#pragma unroll 4
  for (int q = 0; q < IN_DIM/4; ++q) mac_f4(acc, xp[q], w + q*4*EMB);
  float4* hp = (float4*)(h + (size_t)n*EMB);
#pragma unroll
  for (int q = 0; q < 8; ++q) {
    float4 o; o.x = acc[4*q]; o.y = acc[4*q+1]; o.z = acc[4*q+2]; o.w = acc[4*q+3];
    hp[q] = o;
  }
}

// p[n] = h[n] @ W1[0:32], q[n] = h[n] @ W1[32:64]
__global__ __launch_bounds__(256) void k_pq(
    const float* __restrict__ h, const float* __restrict__ w1,
    float* __restrict__ p, float* __restrict__ q)
{
  const int n = blockIdx.x*256 + threadIdx.x;
  if (n >= N_NODES) return;
  float ap[EMB], aq[EMB];
#pragma unroll
  for (int c = 0; c < EMB; ++c) { ap[c] = 0.f; aq[c] = 0.f; }
  const float4* hp = (const float4*)(h + (size_t)n*EMB);
#pragma unroll
  for (int q8 = 0; q8 < 8; ++q8) {
    const float4 v = hp[q8];
    mac_f4(ap, v, w1 + q8*4*EMB);
    mac_f4(aq, v, w1 + (EMB + q8*4)*EMB);
  }
  float4* pp = (float4*)(p + (size_t)n*EMB);
  float4* qp = (float4*)(q + (size_t)n*EMB);
#pragma unroll
  for (int q8 = 0; q8 < 8; ++q8) {
    float4 o1; o1.x = ap[4*q8]; o1.y = ap[4*q8+1]; o1.z = ap[4*q8+2]; o1.w = ap[4*q8+3];
    float4 o2; o2.x = aq[4*q8]; o2.y = aq[4*q8+1]; o2.z = aq[4*q8+2]; o2.w = aq[4*q8+3];
    pp[q8] = o1; qp[q8] = o2;
  }
}

// ---- CSR build ----
__global__ __launch_bounds__(256) void k_hist(const int* __restrict__ ei, int* __restrict__ cnt) {
  const int e = blockIdx.x*256 + threadIdx.x;
  if (e < N_EDGES) atomicAdd(&cnt[ei[N_EDGES + e]], 1);
}

__global__ __launch_bounds__(1024) void k_scan(const int* __restrict__ cnt, int* __restrict__ row_ptr) {
  __shared__ int part[1024];
  const int t = threadIdx.x;
  const int CH = (N_NODES + 1023) / 1024;  // 49
  const int lo = t*CH, hi = min(lo + CH, N_NODES);
  int s = 0;
  for (int i = lo; i < hi; ++i) s += cnt[i];
  part[t] = s;
  __syncthreads();
  for (int o = 1; o < 1024; o <<= 1) {
    int v = (t >= o) ? part[t - o] : 0;
    __syncthreads();
    part[t] += v;
    __syncthreads();
  }
  int run = (t == 0) ? 0 : part[t-1];
  for (int i = lo; i < hi; ++i) { row_ptr[i] = run; run += cnt[i]; }
  if (t == 0) row_ptr[N_NODES] = N_EDGES;
}

__global__ __launch_bounds__(256) void k_place(const int* __restrict__ ei,
                                               const int* __restrict__ row_ptr,
                                               int* __restrict__ cnt, int* __restrict__ perm) {
  const int e = blockIdx.x*256 + threadIdx.x;
  if (e >= N_EDGES) return;
  const int d = ei[N_EDGES + e];
  const int pos = row_ptr[d] + atomicAdd(&cnt[d], 1);
  perm[pos] = e;
}

// Gather edge data into CSR position order (ONE random-read pass per call).
__global__ __launch_bounds__(256) void k_permute(
    const int* __restrict__ perm, const int* __restrict__ ei, const float* __restrict__ ea,
    int* __restrict__ src_perm, int* __restrict__ dst_perm, float* __restrict__ ea_perm)
{
  const int i = blockIdx.x*256 + threadIdx.x;
  const int e = perm[i];
  src_perm[i] = ei[e];
  dst_perm[i] = ei[N_EDGES + e];
  const float4* src4 = (const float4*)(ea + (size_t)e*ED);
  float4* d4 = (float4*)(ea_perm + (size_t)i*ED);
  d4[0] = src4[0];
  d4[1] = src4[1];
}

// y1[i] = b1 + p[dst_perm[i]] + q[src_perm[i]] + ea_perm[i] @ w1b; store bf16 [E][32]; fused stats.
__global__ __launch_bounds__(256) void k_msg1(
    const float* __restrict__ p, const float* __restrict__ q,
    const int* __restrict__ src_perm, const int* __restrict__ dst_perm,
    const float* __restrict__ ea_perm,
    const float* __restrict__ w1b, const float* __restrict__ b1,
    unsigned short* __restrict__ y, float* __restrict__ partial)
{
  float ts[EMB], tss[EMB];
#pragma unroll
  for (int c = 0; c < EMB; ++c) { ts[c] = 0.f; tss[c] = 0.f; }
  const int base = blockIdx.x*(256*MSG1_EPT) + threadIdx.x;
  for (int it = 0; it < MSG1_EPT; ++it) {
    const int i = base + it*256;
    if (i >= N_EDGES) break;
    const int dst = dst_perm[i];
    const int src = src_perm[i];
    float acc[EMB];
    const float4* pd = (const float4*)(p + (size_t)dst*EMB);
    const float4* qs = (const float4*)(q + (size_t)src*EMB);
#pragma unroll
    for (int q8 = 0; q8 < 8; ++q8) {
      const float4 a = pd[q8];
      const float4 b = qs[q8];
      acc[4*q8+0] = b1[4*q8+0] + a.x + b.x;
      acc[4*q8+1] = b1[4*q8+1] + a.y + b.y;
      acc[4*q8+2] = b1[4*q8+2] + a.z + b.z;
      acc[4*q8+3] = b1[4*q8+3] + a.w + b.w;
    }
    const float4* ep = (const float4*)(ea_perm + (size_t)i*ED);
    mac_f4(acc, ep[0], w1b);
    mac_f4(acc, ep[1], w1b + 4*EMB);

    unsigned short us[EMB];
#pragma unroll
    for (int c = 0; c < EMB; ++c) us[c] = f2bf(acc[c]);
    unsigned int u[16];
#pragma unroll
    for (int j = 0; j < 16; ++j)
      u[j] = (unsigned)us[2*j] | ((unsigned)us[2*j+1] << 16);
    uint4* dp = (uint4*)(y + (size_t)i*EMB);
#pragma unroll
    for (int j = 0; j < 4; ++j) {
      uint4 o; o.x = u[4*j]; o.y = u[4*j+1]; o.z = u[4*j+2]; o.w = u[4*j+3];
      dp[j] = o;
    }
#pragma unroll
    for (int c = 0; c < EMB; ++c) {
      const float v = bf2f(us[c]);
      ts[c] += v;
      tss[c] = fmaf(v, v, tss[c]);
    }
  }
  block_partial(ts, tss, partial);
}

// BN finalize from partials, parallel (1024 thr, 16-way row split + LDS tree).
__global__ __launch_bounds__(1024) void k_bnfin(
    const float* __restrict__ partial, int nblocks,
    const float* __restrict__ g, const float* __restrict__ be,
    float* __restrict__ coef, float inv_count)
{
  __shared__ float sred[1024];
  __shared__ float tot[64];
  const int c = threadIdx.x & 63;
  const int r = threadIdx.x >> 6;
  float s = 0.f;
  for (int b = r; b < nblocks; b += 16) s += partial[(size_t)b*64 + c];
  sred[threadIdx.x] = s;
  __syncthreads();
  if (threadIdx.x < 64) {
    float t = 0.f;
#pragma unroll
    for (int m = 0; m < 16; ++m) t += sred[m*64 + threadIdx.x];
    tot[threadIdx.x] = t;
  }
  __syncthreads();
  if (threadIdx.x < EMB) {
    const float mu  = tot[threadIdx.x] * inv_count;
    const float var = tot[EMB + threadIdx.x] * inv_count - mu*mu;
    const float a = g[threadIdx.x] * rsqrtf(var + EPS_BN);
    coef[threadIdx.x] = a;
    coef[EMB + threadIdx.x] = fmaf(-mu, a, be[threadIdx.x]);
  }
}

// MFMA msg2: y2 = bf16( relu(bn1(y1)) @ bf16(W2) + b2 ), in place on y; fused stats.
// 16-edge tiles; A-frag: m=lane&15, k=(lane>>4)*8+j; B-frag: n=lane&15, k=(lane>>4)*8+j;
// C/D: col=lane&15, row=(lane>>4)*4+reg  [m89].
__global__ __launch_bounds__(256) void k_msg2(
    unsigned short* __restrict__ y,
    const float* __restrict__ coef1,
    const float* __restrict__ w2, const float* __restrict__ b2,
    float* __restrict__ partial)
{
  __shared__ __align__(16) unsigned short lds_t[4][16*32];  // per-wave repack tile
  __shared__ float lds_s[4][32], lds_q[4][32];              // per-wave col sum/sumsq

  const int lane = threadIdx.x & 63;
  const int wid  = threadIdx.x >> 6;
  const int n0 = lane & 15;
  const int kb = lane >> 4;   // 0..3

  // B fragments (W2 -> bf16), loaded once; W2 is [k][n] row-major
  bf16x8 Blo, Bhi;
#pragma unroll
  for (int j = 0; j < 8; ++j) {
    Blo[j] = (short)f2bf(w2[(kb*8 + j)*EMB + n0]);
    Bhi[j] = (short)f2bf(w2[(kb*8 + j)*EMB + 16 + n0]);
  }
  // BN1 coefs for this lane's k-range
  float a1[8], c1[8];
#pragma unroll
  for (int j = 0; j < 8; ++j) {
    a1[j] = coef1[kb*8 + j];
    c1[j] = coef1[EMB + kb*8 + j];
  }
  const float b2c0 = b2[n0], b2c1 = b2[16 + n0];

  // stats accumulators (post-repack layout: row=lane>>2, cols=(lane&3)*8+j)
  float ts[8], tss[8];
#pragma unroll
  for (int j = 0; j < 8; ++j) { ts[j] = 0.f; tss[j] = 0.f; }

  const int tile0 = blockIdx.x * (MSG2_TPW*4);
  for (int t = 0; t < MSG2_TPW; ++t) {
    const int tile = tile0 + t*4 + wid;
    if (tile >= NT16) break;
    const size_t e0 = (size_t)tile * 16;

    // A fragment: row e0+n0, k = kb*8..kb*8+7 (16 contiguous bytes)
    const uint4 araw = *(const uint4*)(y + (e0 + n0)*EMB + kb*8);
    unsigned int ua[4] = {araw.x, araw.y, araw.z, araw.w};
    bf16x8 A;
#pragma unroll
    for (int j = 0; j < 4; ++j) {
      float v0 = bf2f((unsigned short)(ua[j] & 0xFFFFu));
      float v1 = bf2f((unsigned short)(ua[j] >> 16));
      v0 = fmaxf(fmaf(a1[2*j],   v0, c1[2*j]),   0.f);
      v1 = fmaxf(fmaf(a1[2*j+1], v1, c1[2*j+1]), 0.f);
      A[2*j]   = (short)f2bf(v0);
      A[2*j+1] = (short)f2bf(v1);
    }

    f32x4 acc0 = {0.f, 0.f, 0.f, 0.f};
    f32x4 acc1 = {0.f, 0.f, 0.f, 0.f};
    acc0 = __builtin_amdgcn_mfma_f32_16x16x32_bf16(A, Blo, acc0, 0, 0, 0);
    acc1 = __builtin_amdgcn_mfma_f32_16x16x32_bf16(A, Bhi, acc1, 0, 0, 0);

    // quantize + repack via wave-private LDS (DS ops are wave-ordered; no barrier)
#pragma unroll
    for (int r = 0; r < 4; ++r) {
      const int row = kb*4 + r;
      lds_t[wid][row*32 + n0]      = f2bf(acc0[r] + b2c0);
      lds_t[wid][row*32 + 16 + n0] = f2bf(acc1[r] + b2c1);
    }
    const uint4 orow = *(const uint4*)&lds_t[wid][(lane>>2)*32 + (lane&3)*8];
    *(uint4*)(y + (e0 + (lane>>2))*EMB + (lane&3)*8) = orow;

    // stats on quantized values
    unsigned int uo[4] = {orow.x, orow.y, orow.z, orow.w};
#pragma unroll
    for (int j = 0; j < 4; ++j) {
      const float v0 = bf2f((unsigned short)(uo[j] & 0xFFFFu));
      const float v1 = bf2f((unsigned short)(uo[j] >> 16));
      ts[2*j]   += v0;  tss[2*j]   = fmaf(v0, v0, tss[2*j]);
      ts[2*j+1] += v1;  tss[2*j+1] = fmaf(v1, v1, tss[2*j+1]);
    }
  }

  // reduce over the 16 lanes sharing (lane&3)
#pragma unroll
  for (int j = 0; j < 8; ++j) {
    float s = ts[j], qq = tss[j];
#pragma unroll
    for (int o = 4; o < 64; o <<= 1) {
      s  += __shfl_xor(s, o, 64);
      qq += __shfl_xor(qq, o, 64);
    }
    ts[j] = s; tss[j] = qq;
  }
  if (lane < 4) {
#pragma unroll
    for (int j = 0; j < 8; ++j) {
      lds_s[wid][lane*8 + j] = ts[j];
      lds_q[wid][lane*8 + j] = tss[j];
    }
  }
  __syncthreads();
  if (threadIdx.x < 64) {
    const int c = threadIdx.x & 31;
    const int kind = threadIdx.x >> 5;
    float v = 0.f;
#pragma unroll
    for (int wq = 0; wq < 4; ++wq)
      v += kind ? lds_q[wq][c] : lds_s[wq][c];
    partial[(size_t)blockIdx.x*64 + kind*32 + c] = v;
  }
}

// CSR gather, sequential: aggr[n][c] = sum_{i in [lo,hi)} relu(bn2(y[i][c]))
__global__ __launch_bounds__(256) void k_aggr(
    const unsigned short* __restrict__ y, const int* __restrict__ row_ptr,
    const float* __restrict__ coef2, float* __restrict__ aggr)
{
  const int g = threadIdx.x >> 5;
  const int c = threadIdx.x & 31;
  const int n = blockIdx.x*8 + g;
  if (n >= N_NODES) return;
  const float a = coef2[c], b = coef2[EMB + c];
  const int lo = row_ptr[n], hi = row_ptr[n+1];
  float s = 0.f;
  for (int i = lo; i < hi; ++i) {
    const float v = bf2f(y[(size_t)i*EMB + c]);
    s += fmaxf(fmaf(a, v, b), 0.f);
  }
  aggr[(size_t)n*EMB + c] = s;
}

// z1 = concat(h, aggr) @ uw1 + b, written IN PLACE into aggr. stats.
__global__ __launch_bounds__(256) void k_upd1(
    const float* __restrict__ h, float* __restrict__ aggr,
    const float* __restrict__ w, const float* __restrict__ b,
    float* __restrict__ partial)
{
  const int n = blockIdx.x*256 + threadIdx.x;
  float acc[EMB];
#pragma unroll
  for (int c = 0; c < EMB; ++c) acc[c] = 0.f;
  if (n < N_NODES) {
#pragma unroll
    for (int c = 0; c < EMB; ++c) acc[c] = b[c];
    const float4* hp = (const float4*)(h + (size_t)n*EMB);
    const float4* ap = (const float4*)(aggr + (size_t)n*EMB);
#pragma unroll
    for (int q8 = 0; q8 < 8; ++q8) mac_f4(acc, hp[q8], w + q8*4*EMB);
#pragma unroll
    for (int q8 = 0; q8 < 8; ++q8) mac_f4(acc, ap[q8], w + (EMB + q8*4)*EMB);
    float4* zp = (float4*)(aggr + (size_t)n*EMB);
#pragma unroll
    for (int q8 = 0; q8 < 8; ++q8) {
      float4 o; o.x = acc[4*q8]; o.y = acc[4*q8+1]; o.z = acc[4*q8+2]; o.w = acc[4*q8+3];
      zp[q8] = o;
    }
  }
  float ts[EMB], tss[EMB];
#pragma unroll
  for (int c = 0; c < EMB; ++c) { ts[c] = acc[c]; tss[c] = acc[c]*acc[c]; }
  block_partial(ts, tss, partial);
}

// z2 = relu(bn(z1)) @ uw2 + b, in place. stats.
__global__ __launch_bounds__(256) void k_upd2(
    float* __restrict__ z, const float* __restrict__ coef1,
    const float* __restrict__ w, const float* __restrict__ b,
    float* __restrict__ partial)
{
  const int n = blockIdx.x*256 + threadIdx.x;
  float acc[EMB];
#pragma unroll
  for (int c = 0; c < EMB; ++c) acc[c] = 0.f;
  if (n < N_NODES) {
#pragma unroll
    for (int c = 0; c < EMB; ++c) acc[c] = b[c];
    const float4* zp = (const float4*)(z + (size_t)n*EMB);
#pragma unroll
    for (int q8 = 0; q8 < 8; ++q8) {
      const float4 v = zp[q8];
      float mv[4] = {v.x, v.y, v.z, v.w};
#pragma unroll
      for (int j = 0; j < 4; ++j) {
        const int k = 4*q8 + j;
        const float m = fmaxf(fmaf(coef1[k], mv[j], coef1[EMB + k]), 0.f);
        const float* wk = w + k*EMB;
#pragma unroll
        for (int c = 0; c < EMB; ++c) acc[c] = fmaf(m, wk[c], acc[c]);
      }
    }
    float4* op = (float4*)(z + (size_t)n*EMB);
#pragma unroll
    for (int q8 = 0; q8 < 8; ++q8) {
      float4 o; o.x = acc[4*q8]; o.y = acc[4*q8+1]; o.z = acc[4*q8+2]; o.w = acc[4*q8+3];
      op[q8] = o;
    }
  }
  float ts[EMB], tss[EMB];
#pragma unroll
  for (int c = 0; c < EMB; ++c) { ts[c] = acc[c]; tss[c] = acc[c]*acc[c]; }
  block_partial(ts, tss, partial);
}

// h += relu(bn(z2))
__global__ __launch_bounds__(256) void k_resid(
    float* __restrict__ h, const float* __restrict__ z, const float* __restrict__ coef)
{
  const int t = blockIdx.x*256 + threadIdx.x;
  const int c = t & (EMB-1);
  const float v = fmaf(coef[c], z[t], coef[EMB + c]);
  h[t] += fmaxf(v, 0.f);
}

// per-graph mean pool + final linear
__global__ void k_pool(const float* __restrict__ h, const int* __restrict__ batch,
                       const float* __restrict__ pw, const float* __restrict__ pb,
                       float* __restrict__ out)
{
  __shared__ float sred[256];
  __shared__ float hg[EMB];
  const int b = blockIdx.x;
  int lo = 0, hi = N_NODES;
  while (lo < hi) { int m = (lo + hi) >> 1; if (batch[m] < b) lo = m + 1; else hi = m; }
  const int start = lo;
  hi = N_NODES;
  while (lo < hi) { int m = (lo + hi) >> 1; if (batch[m] < b + 1) lo = m + 1; else hi = m; }
  const int end = lo;

  const int c = threadIdx.x & (EMB-1);
  const int r = threadIdx.x >> 5;
  float s = 0.f;
  for (int n = start + r; n < end; n += 8) s += h[(size_t)n*EMB + c];
  sred[threadIdx.x] = s;
  __syncthreads();
  if (threadIdx.x < EMB) {
    float tot = 0.f;
#pragma unroll
    for (int r2 = 0; r2 < 8; ++r2) tot += sred[r2*EMB + threadIdx.x];
    const float cnt = (float)(end - start);
    hg[threadIdx.x] = tot / fmaxf(cnt, 1.f);
  }
  __syncthreads();
  if (threadIdx.x < OUTD) {
    float acc = pb[threadIdx.x];
#pragma unroll
    for (int cc = 0; cc < EMB; ++cc) acc = fmaf(hg[cc], pw[cc*OUTD + threadIdx.x], acc);
    out[b*OUTD + threadIdx.x] = acc;
  }
}

// ---------------- host ----------------

extern "C" void kernel_launch(void* const* d_in, const int* in_sizes, int n_in,
                              void* d_out, int out_size, void* d_ws, size_t ws_size,
                              hipStream_t stream) {
  const float* x        = (const float*)d_in[0];
  const int*   ei       = (const int*)  d_in[1];
  const float* ea       = (const float*)d_in[2];
  const int*   batch    = (const int*)  d_in[3];
  const float* lin_in_w = (const float*)d_in[4];
  const float* lin_in_b = (const float*)d_in[5];
  const float* msg_w1   = (const float*)d_in[6];
  const float* msg_b1   = (const float*)d_in[7];
  const float* msg_g1   = (const float*)d_in[8];
  const float* msg_be1  = (const float*)d_in[9];
  const float* msg_w2   = (const float*)d_in[10];
  const float* msg_b2   = (const float*)d_in[11];
  const float* msg_g2   = (const float*)d_in[12];
  const float* msg_be2  = (const float*)d_in[13];
  const float* upd_w1   = (const float*)d_in[14];
  const float* upd_b1   = (const float*)d_in[15];
  const float* upd_g1   = (const float*)d_in[16];
  const float* upd_be1  = (const float*)d_in[17];
  const float* upd_w2   = (const float*)d_in[18];
  const float* upd_b2   = (const float*)d_in[19];
  const float* upd_g2   = (const float*)d_in[20];
  const float* upd_be2  = (const float*)d_in[21];
  const float* pred_w   = (const float*)d_in[22];
  const float* pred_b   = (const float*)d_in[23];
  float* out = (float*)d_out;

  // Workspace layout (~113 MB)
  char* wsb = (char*)d_ws;
  unsigned short* y = (unsigned short*)wsb;             // E*32 bf16 (y1 then y2 in place)
  float* ea_perm = (float*)(wsb + (size_t)N_EDGES*EMB*2);
  float* h       = ea_perm + (size_t)N_EDGES*ED;
  float* p       = h    + (size_t)N_NODES*EMB;
  float* q       = p    + (size_t)N_NODES*EMB;
  float* aggr    = q    + (size_t)N_NODES*EMB;          // also z1/z2 in place
  float* partial = aggr + (size_t)N_NODES*EMB;          // 3200 rows x 64
  float* coef    = partial + (size_t)3200*64;           // 16 stages x 64
  int*   perm    = (int*)(coef + 16*64);
  int*   src_perm= perm + N_EDGES;
  int*   dst_perm= src_perm + N_EDGES;
  int*   cnt     = dst_perm + N_EDGES;
  int*   row_ptr = cnt + N_NODES;
  const size_t need = ((size_t)((char*)(row_ptr + N_NODES + 1) - wsb));
  if (ws_size < need) return;

  const float invE = 1.0f / (float)N_EDGES;
  const float invN = 1.0f / (float)N_NODES;

  // input projection + CSR build + edge-data permute (once per call)
  k_lin_in<<<NODE_GRID, 256, 0, stream>>>(x, lin_in_w, lin_in_b, h);
  hipMemsetAsync(cnt, 0, N_NODES*sizeof(int), stream);
  k_hist<<<EDGE_GRID, 256, 0, stream>>>(ei, cnt);
  k_scan<<<1, 1024, 0, stream>>>(cnt, row_ptr);
  hipMemsetAsync(cnt, 0, N_NODES*sizeof(int), stream);
  k_place<<<EDGE_GRID, 256, 0, stream>>>(ei, row_ptr, cnt, perm);
  k_permute<<<EDGE_GRID, 256, 0, stream>>>(perm, ei, ea, src_perm, dst_perm, ea_perm);

  for (int l = 0; l < NLAYERS; ++l) {
    const int st = l*4;
    const float* w1  = msg_w1 + (size_t)l*(2*EMB+ED)*EMB;
    const float* w1b = w1 + (size_t)2*EMB*EMB;  // ea rows
    const float* w2  = msg_w2 + (size_t)l*EMB*EMB;
    const float* uw1 = upd_w1 + (size_t)l*(2*EMB)*EMB;
    const float* uw2 = upd_w2 + (size_t)l*EMB*EMB;

    k_pq<<<NODE_GRID, 256, 0, stream>>>(h, w1, p, q);
    k_msg1<<<MSG1_GRID, 256, 0, stream>>>(p, q, src_perm, dst_perm, ea_perm,
                                          w1b, msg_b1 + l*EMB, y, partial);
    k_bnfin<<<1, 1024, 0, stream>>>(partial, MSG1_GRID, msg_g1 + l*EMB, msg_be1 + l*EMB,
                                    coef + st*64, invE);
    k_msg2<<<MSG2_GRID, 256, 0, stream>>>(y, coef + st*64, w2, msg_b2 + l*EMB, partial);
    k_bnfin<<<1, 1024, 0, stream>>>(partial, MSG2_GRID, msg_g2 + l*EMB, msg_be2 + l*EMB,
                                    coef + (st+1)*64, invE);
    k_aggr<<<AGGR_GRID, 256, 0, stream>>>(y, row_ptr, coef + (st+1)*64, aggr);
    k_upd1<<<NODE_GRID, 256, 0, stream>>>(h, aggr, uw1, upd_b1 + l*EMB, partial);
    k_bnfin<<<1, 1024, 0, stream>>>(partial, NODE_GRID, upd_g1 + l*EMB, upd_be1 + l*EMB,
                                    coef + (st+2)*64, invN);
    k_upd2<<<NODE_GRID, 256, 0, stream>>>(aggr, coef + (st+2)*64, uw2, upd_b2 + l*EMB, partial);
    k_bnfin<<<1, 1024, 0, stream>>>(partial, NODE_GRID, upd_g2 + l*EMB, upd_be2 + l*EMB,
                                    coef + (st+3)*64, invN);
    k_resid<<<ELEM_GRID, 256, 0, stream>>>(h, aggr, coef + (st+3)*64);
  }

  k_pool<<<NB, 256, 0, stream>>>(h, batch, pred_w, pred_b, out);
}

// Round 6
// 1159.468 us; speedup vs baseline: 1.6191x; 1.1068x over previous
//
#include <hip/hip_runtime.h>
#include <cstddef>

// Problem constants
#define N_NODES 50000
#define N_EDGES 800000
#define IN_DIM  128
#define EMB     32
#define ED      8
#define NLAYERS 4
#define NB      64
#define OUTD    10
#define EPS_BN  1e-5f

#define EDGE_GRID 3125   // 800000/256 exact
#define NODE_GRID 196    // ceil(50000/256)
#define AGGR_GRID 6250   // 50000/8
#define MSG1_EPT  4
#define MSG1_GRID 782    // ceil(800000/1024)
#define NT16      50000  // 800000/16
#define MSG2_TPW  16
#define MSG2_GRID 782

typedef short bf16x8 __attribute__((ext_vector_type(8)));
typedef float f32x4  __attribute__((ext_vector_type(4)));

// ---------------- helpers ----------------

__device__ __forceinline__ unsigned short f2bf(float x) {
  union { float f; unsigned u; } v; v.f = x;
  unsigned b = v.u + 0x7FFFu + ((v.u >> 16) & 1u);
  return (unsigned short)(b >> 16);
}
__device__ __forceinline__ float bf2f(unsigned short s) {
  union { unsigned u; float f; } v; v.u = ((unsigned)s) << 16;
  return v.f;
}

__device__ __forceinline__ void mac_f4(float acc[EMB], const float4 v, const float* __restrict__ wk) {
#pragma unroll
  for (int c = 0; c < EMB; ++c) acc[c] = fmaf(v.x, wk[c], acc[c]);
#pragma unroll
  for (int c = 0; c < EMB; ++c) acc[c] = fmaf(v.y, wk[EMB + c], acc[c]);
#pragma unroll
  for (int c = 0; c < EMB; ++c) acc[c] = fmaf(v.z, wk[2*EMB + c], acc[c]);
#pragma unroll
  for (int c = 0; c < EMB; ++c) acc[c] = fmaf(v.w, wk[3*EMB + c], acc[c]);
}

// Block reduce (sum[32], sumsq[32]) -> 64 fp32 atomicAdds into stats (sum[0..31], sumsq[32..63]).
__device__ __forceinline__ void block_stats_atomic(const float ts[EMB], const float tss[EMB],
                                                   float* __restrict__ stats) {
  __shared__ float sred[256];
  const int lane = threadIdx.x & 63;
  const int wid  = threadIdx.x >> 6;
#pragma unroll
  for (int c = 0; c < EMB; ++c) {
    float a = ts[c];
    float q = tss[c];
#pragma unroll
    for (int o = 32; o > 0; o >>= 1) {
      a += __shfl_down(a, o, 64);
      q += __shfl_down(q, o, 64);
    }
    if (lane == 0) { sred[wid*64 + c] = a; sred[wid*64 + EMB + c] = q; }
  }
  __syncthreads();
  if (threadIdx.x < 64) {
    const float v = sred[threadIdx.x] + sred[64 + threadIdx.x] +
                    sred[128 + threadIdx.x] + sred[192 + threadIdx.x];
    atomicAdd(stats + threadIdx.x, v);
  }
}

// Inline BN-coef preamble: cf[c]=a, cf[32+c]=be-mu*a (LDS). Requires __syncthreads after.
__device__ __forceinline__ void coef_from_stats(const float* __restrict__ stats,
                                                const float* __restrict__ g,
                                                const float* __restrict__ be,
                                                float inv_count, float* __restrict__ cf) {
  if (threadIdx.x < EMB) {
    const int c = threadIdx.x;
    const float mu  = stats[c] * inv_count;
    const float var = stats[EMB + c] * inv_count - mu*mu;
    const float a = g[c] * rsqrtf(var + EPS_BN);
    cf[c] = a;
    cf[EMB + c] = fmaf(-mu, a, be[c]);
  }
  __syncthreads();
}

// ---------------- kernels ----------------

// h = x @ lin_in_w + lin_in_b ; then p/q for layer 0 fused.
__global__ __launch_bounds__(256) void k_lin_in_pq(
    const float* __restrict__ x, const float* __restrict__ w, const float* __restrict__ b,
    const float* __restrict__ w1, float* __restrict__ h,
    float* __restrict__ p, float* __restrict__ q)
{
  const int n = blockIdx.x*256 + threadIdx.x;
  if (n >= N_NODES) return;
  float acc[EMB];
#pragma unroll
  for (int c = 0; c < EMB; ++c) acc[c] = b[c];
  const float4* xp = (const float4*)(x + (size_t)n*IN_DIM);
#pragma unroll 4
  for (int q8 = 0; q8 < IN_DIM/4; ++q8) mac_f4(acc, xp[q8], w + q8*4*EMB);
  float4* hp = (float4*)(h + (size_t)n*EMB);
#pragma unroll
  for (int q8 = 0; q8 < 8; ++q8) {
    float4 o; o.x = acc[4*q8]; o.y = acc[4*q8+1]; o.z = acc[4*q8+2]; o.w = acc[4*q8+3];
    hp[q8] = o;
  }
  float ap[EMB], aq[EMB];
#pragma unroll
  for (int c = 0; c < EMB; ++c) { ap[c] = 0.f; aq[c] = 0.f; }
#pragma unroll
  for (int q8 = 0; q8 < 8; ++q8) {
    float4 v; v.x = acc[4*q8]; v.y = acc[4*q8+1]; v.z = acc[4*q8+2]; v.w = acc[4*q8+3];
    mac_f4(ap, v, w1 + q8*4*EMB);
    mac_f4(aq, v, w1 + (EMB + q8*4)*EMB);
  }
  float4* pp = (float4*)(p + (size_t)n*EMB);
  float4* qp = (float4*)(q + (size_t)n*EMB);
#pragma unroll
  for (int q8 = 0; q8 < 8; ++q8) {
    float4 o1; o1.x = ap[4*q8]; o1.y = ap[4*q8+1]; o1.z = ap[4*q8+2]; o1.w = ap[4*q8+3];
    float4 o2; o2.x = aq[4*q8]; o2.y = aq[4*q8+1]; o2.z = aq[4*q8+2]; o2.w = aq[4*q8+3];
    pp[q8] = o1; qp[q8] = o2;
  }
}

// ---- CSR build ----
__global__ __launch_bounds__(256) void k_hist(const int* __restrict__ ei, int* __restrict__ cnt) {
  const int e = blockIdx.x*256 + threadIdx.x;
  if (e < N_EDGES) atomicAdd(&cnt[ei[N_EDGES + e]], 1);
}

// hierarchical scan, phase A: per-block (256 nodes) exclusive scan + block total
__global__ __launch_bounds__(256) void k_scan_a(const int* __restrict__ cnt,
                                                int* __restrict__ row_ptr, int* __restrict__ bsum) {
  __shared__ int s[256];
  const int gid = blockIdx.x*256 + threadIdx.x;
  const int v = (gid < N_NODES) ? cnt[gid] : 0;
  s[threadIdx.x] = v;
  __syncthreads();
  for (int o = 1; o < 256; o <<= 1) {
    const int t = (threadIdx.x >= o) ? s[threadIdx.x - o] : 0;
    __syncthreads();
    s[threadIdx.x] += t;
    __syncthreads();
  }
  if (gid < N_NODES) row_ptr[gid] = s[threadIdx.x] - v;  // exclusive within block
  if (threadIdx.x == 255) bsum[blockIdx.x] = s[255];
}

// phase B: scan the 196 block totals (in place -> exclusive)
__global__ __launch_bounds__(256) void k_scan_b(int* __restrict__ bsum, int* __restrict__ row_ptr) {
  __shared__ int s[256];
  const int v = (threadIdx.x < NODE_GRID) ? bsum[threadIdx.x] : 0;
  s[threadIdx.x] = v;
  __syncthreads();
  for (int o = 1; o < 256; o <<= 1) {
    const int t = (threadIdx.x >= o) ? s[threadIdx.x - o] : 0;
    __syncthreads();
    s[threadIdx.x] += t;
    __syncthreads();
  }
  if (threadIdx.x < NODE_GRID) bsum[threadIdx.x] = s[threadIdx.x] - v;  // exclusive
  if (threadIdx.x == 0) row_ptr[N_NODES] = N_EDGES;
}

// phase C: add block offsets
__global__ __launch_bounds__(256) void k_scan_c(int* __restrict__ row_ptr, const int* __restrict__ bsum) {
  const int gid = blockIdx.x*256 + threadIdx.x;
  if (gid < N_NODES) row_ptr[gid] += bsum[blockIdx.x];
}

__global__ __launch_bounds__(256) void k_place(const int* __restrict__ ei,
                                               const int* __restrict__ row_ptr,
                                               int* __restrict__ cnt2, int* __restrict__ perm) {
  const int e = blockIdx.x*256 + threadIdx.x;
  if (e >= N_EDGES) return;
  const int d = ei[N_EDGES + e];
  const int pos = row_ptr[d] + atomicAdd(&cnt2[d], 1);
  perm[pos] = e;
}

// Gather edge data into CSR position order (ONE random-read pass per call).
__global__ __launch_bounds__(256) void k_permute(
    const int* __restrict__ perm, const int* __restrict__ ei, const float* __restrict__ ea,
    int* __restrict__ src_perm, int* __restrict__ dst_perm, float* __restrict__ ea_perm)
{
  const int i = blockIdx.x*256 + threadIdx.x;
  const int e = perm[i];
  src_perm[i] = ei[e];
  dst_perm[i] = ei[N_EDGES + e];
  const float4* src4 = (const float4*)(ea + (size_t)e*ED);
  float4* d4 = (float4*)(ea_perm + (size_t)i*ED);
  d4[0] = src4[0];
  d4[1] = src4[1];
}

// y1[i] = b1 + p[dst_perm[i]] + q[src_perm[i]] + ea_perm[i] @ w1b; store bf16 [E][32]; stats -> atomics.
__global__ __launch_bounds__(256) void k_msg1(
    const float* __restrict__ p, const float* __restrict__ q,
    const int* __restrict__ src_perm, const int* __restrict__ dst_perm,
    const float* __restrict__ ea_perm,
    const float* __restrict__ w1b, const float* __restrict__ b1,
    unsigned short* __restrict__ y, float* __restrict__ stats)
{
  float ts[EMB], tss[EMB];
#pragma unroll
  for (int c = 0; c < EMB; ++c) { ts[c] = 0.f; tss[c] = 0.f; }
  const int base = blockIdx.x*(256*MSG1_EPT) + threadIdx.x;
  for (int it = 0; it < MSG1_EPT; ++it) {
    const int i = base + it*256;
    if (i >= N_EDGES) break;
    const int dst = dst_perm[i];
    const int src = src_perm[i];
    float acc[EMB];
    const float4* pd = (const float4*)(p + (size_t)dst*EMB);
    const float4* qs = (const float4*)(q + (size_t)src*EMB);
#pragma unroll
    for (int q8 = 0; q8 < 8; ++q8) {
      const float4 a = pd[q8];
      const float4 b = qs[q8];
      acc[4*q8+0] = b1[4*q8+0] + a.x + b.x;
      acc[4*q8+1] = b1[4*q8+1] + a.y + b.y;
      acc[4*q8+2] = b1[4*q8+2] + a.z + b.z;
      acc[4*q8+3] = b1[4*q8+3] + a.w + b.w;
    }
    const float4* ep = (const float4*)(ea_perm + (size_t)i*ED);
    mac_f4(acc, ep[0], w1b);
    mac_f4(acc, ep[1], w1b + 4*EMB);

    unsigned short us[EMB];
#pragma unroll
    for (int c = 0; c < EMB; ++c) us[c] = f2bf(acc[c]);
    unsigned int u[16];
#pragma unroll
    for (int j = 0; j < 16; ++j)
      u[j] = (unsigned)us[2*j] | ((unsigned)us[2*j+1] << 16);
    uint4* dp = (uint4*)(y + (size_t)i*EMB);
#pragma unroll
    for (int j = 0; j < 4; ++j) {
      uint4 o; o.x = u[4*j]; o.y = u[4*j+1]; o.z = u[4*j+2]; o.w = u[4*j+3];
      dp[j] = o;
    }
#pragma unroll
    for (int c = 0; c < EMB; ++c) {
      const float v = bf2f(us[c]);
      ts[c] += v;
      tss[c] = fmaf(v, v, tss[c]);
    }
  }
  block_stats_atomic(ts, tss, stats);
}

// MFMA msg2: y2 = bf16( relu(bn1(y1)) @ bf16(W2) + b2 ), in place on y; coef inline; stats -> atomics.
__global__ __launch_bounds__(256) void k_msg2(
    unsigned short* __restrict__ y,
    const float* __restrict__ stats1, const float* __restrict__ g1, const float* __restrict__ be1,
    const float* __restrict__ w2, const float* __restrict__ b2,
    float* __restrict__ stats2)
{
  __shared__ __align__(16) unsigned short lds_t[4][16*32];
  __shared__ float lds_s[4][32], lds_q[4][32];
  __shared__ float cf[64];

  coef_from_stats(stats1, g1, be1, 1.0f/(float)N_EDGES, cf);

  const int lane = threadIdx.x & 63;
  const int wid  = threadIdx.x >> 6;
  const int n0 = lane & 15;
  const int kb = lane >> 4;   // 0..3

  bf16x8 Blo, Bhi;
#pragma unroll
  for (int j = 0; j < 8; ++j) {
    Blo[j] = (short)f2bf(w2[(kb*8 + j)*EMB + n0]);
    Bhi[j] = (short)f2bf(w2[(kb*8 + j)*EMB + 16 + n0]);
  }
  float a1[8], c1[8];
#pragma unroll
  for (int j = 0; j < 8; ++j) {
    a1[j] = cf[kb*8 + j];
    c1[j] = cf[EMB + kb*8 + j];
  }
  const float b2c0 = b2[n0], b2c1 = b2[16 + n0];

  float ts[8], tss[8];
#pragma unroll
  for (int j = 0; j < 8; ++j) { ts[j] = 0.f; tss[j] = 0.f; }

  const int tile0 = blockIdx.x * (MSG2_TPW*4);
  for (int t = 0; t < MSG2_TPW; ++t) {
    const int tile = tile0 + t*4 + wid;
    if (tile >= NT16) break;
    const size_t e0 = (size_t)tile * 16;

    const uint4 araw = *(const uint4*)(y + (e0 + n0)*EMB + kb*8);
    unsigned int ua[4] = {araw.x, araw.y, araw.z, araw.w};
    bf16x8 A;
#pragma unroll
    for (int j = 0; j < 4; ++j) {
      float v0 = bf2f((unsigned short)(ua[j] & 0xFFFFu));
      float v1 = bf2f((unsigned short)(ua[j] >> 16));
      v0 = fmaxf(fmaf(a1[2*j],   v0, c1[2*j]),   0.f);
      v1 = fmaxf(fmaf(a1[2*j+1], v1, c1[2*j+1]), 0.f);
      A[2*j]   = (short)f2bf(v0);
      A[2*j+1] = (short)f2bf(v1);
    }

    f32x4 acc0 = {0.f, 0.f, 0.f, 0.f};
    f32x4 acc1 = {0.f, 0.f, 0.f, 0.f};
    acc0 = __builtin_amdgcn_mfma_f32_16x16x32_bf16(A, Blo, acc0, 0, 0, 0);
    acc1 = __builtin_amdgcn_mfma_f32_16x16x32_bf16(A, Bhi, acc1, 0, 0, 0);

#pragma unroll
    for (int r = 0; r < 4; ++r) {
      const int row = kb*4 + r;
      lds_t[wid][row*32 + n0]      = f2bf(acc0[r] + b2c0);
      lds_t[wid][row*32 + 16 + n0] = f2bf(acc1[r] + b2c1);
    }
    const uint4 orow = *(const uint4*)&lds_t[wid][(lane>>2)*32 + (lane&3)*8];
    *(uint4*)(y + (e0 + (lane>>2))*EMB + (lane&3)*8) = orow;

    unsigned int uo[4] = {orow.x, orow.y, orow.z, orow.w};
#pragma unroll
    for (int j = 0; j < 4; ++j) {
      const float v0 = bf2f((unsigned short)(uo[j] & 0xFFFFu));
      const float v1 = bf2f((unsigned short)(uo[j] >> 16));
      ts[2*j]   += v0;  tss[2*j]   = fmaf(v0, v0, tss[2*j]);
      ts[2*j+1] += v1;  tss[2*j+1] = fmaf(v1, v1, tss[2*j+1]);
    }
  }

#pragma unroll
  for (int j = 0; j < 8; ++j) {
    float s = ts[j], qq = tss[j];
#pragma unroll
    for (int o = 4; o < 64; o <<= 1) {
      s  += __shfl_xor(s, o, 64);
      qq += __shfl_xor(qq, o, 64);
    }
    ts[j] = s; tss[j] = qq;
  }
  if (lane < 4) {
#pragma unroll
    for (int j = 0; j < 8; ++j) {
      lds_s[wid][lane*8 + j] = ts[j];
      lds_q[wid][lane*8 + j] = tss[j];
    }
  }
  __syncthreads();
  if (threadIdx.x < 64) {
    const int c = threadIdx.x & 31;
    const int kind = threadIdx.x >> 5;
    float v = 0.f;
#pragma unroll
    for (int wq = 0; wq < 4; ++wq)
      v += kind ? lds_q[wq][c] : lds_s[wq][c];
    atomicAdd(stats2 + kind*32 + c, v);
  }
}

// CSR gather, sequential, 2 cols/lane + 2 rows/iter; coef inline.
__global__ __launch_bounds__(256) void k_aggr(
    const unsigned short* __restrict__ y, const int* __restrict__ row_ptr,
    const float* __restrict__ stats2, const float* __restrict__ g2, const float* __restrict__ be2,
    float* __restrict__ aggr)
{
  __shared__ float cf[64];
  coef_from_stats(stats2, g2, be2, 1.0f/(float)N_EDGES, cf);

  const int grp = threadIdx.x >> 5;  // 0..7
  const int l   = threadIdx.x & 31;
  const int rof = l >> 4;            // 0..1 row offset
  const int cp  = l & 15;            // column pair
  const int n = blockIdx.x*8 + grp;
  if (n >= N_NODES) return;
  const float a0 = cf[2*cp],     b0 = cf[EMB + 2*cp];
  const float a1 = cf[2*cp + 1], b1 = cf[EMB + 2*cp + 1];
  const int lo = row_ptr[n], hi = row_ptr[n+1];
  float s0 = 0.f, s1 = 0.f;
  for (int i = lo + rof; i < hi; i += 2) {
    const unsigned u = *(const unsigned*)(y + (size_t)i*EMB + 2*cp);
    const float v0 = bf2f((unsigned short)(u & 0xFFFFu));
    const float v1 = bf2f((unsigned short)(u >> 16));
    s0 += fmaxf(fmaf(a0, v0, b0), 0.f);
    s1 += fmaxf(fmaf(a1, v1, b1), 0.f);
  }
  s0 += __shfl_xor(s0, 16, 64);
  s1 += __shfl_xor(s1, 16, 64);
  if (rof == 0) {
    float2 o; o.x = s0; o.y = s1;
    *(float2*)(aggr + (size_t)n*EMB + 2*cp) = o;
  }
}

// z1 = concat(h, aggr) @ uw1 + b, IN PLACE into aggr. stats -> atomics.
__global__ __launch_bounds__(256) void k_upd1(
    const float* __restrict__ h, float* __restrict__ aggr,
    const float* __restrict__ w, const float* __restrict__ b,
    float* __restrict__ stats)
{
  const int n = blockIdx.x*256 + threadIdx.x;
  float acc[EMB];
#pragma unroll
  for (int c = 0; c < EMB; ++c) acc[c] = 0.f;
  if (n < N_NODES) {
#pragma unroll
    for (int c = 0; c < EMB; ++c) acc[c] = b[c];
    const float4* hp = (const float4*)(h + (size_t)n*EMB);
    const float4* ap = (const float4*)(aggr + (size_t)n*EMB);
#pragma unroll
    for (int q8 = 0; q8 < 8; ++q8) mac_f4(acc, hp[q8], w + q8*4*EMB);
#pragma unroll
    for (int q8 = 0; q8 < 8; ++q8) mac_f4(acc, ap[q8], w + (EMB + q8*4)*EMB);
    float4* zp = (float4*)(aggr + (size_t)n*EMB);
#pragma unroll
    for (int q8 = 0; q8 < 8; ++q8) {
      float4 o; o.x = acc[4*q8]; o.y = acc[4*q8+1]; o.z = acc[4*q8+2]; o.w = acc[4*q8+3];
      zp[q8] = o;
    }
  }
  float ts[EMB], tss[EMB];
#pragma unroll
  for (int c = 0; c < EMB; ++c) { ts[c] = acc[c]; tss[c] = acc[c]*acc[c]; }
  block_stats_atomic(ts, tss, stats);
}

// z2 = relu(bn(z1)) @ uw2 + b, in place; coef inline; stats -> atomics.
__global__ __launch_bounds__(256) void k_upd2(
    float* __restrict__ z,
    const float* __restrict__ stats1, const float* __restrict__ g1, const float* __restrict__ be1,
    const float* __restrict__ w, const float* __restrict__ b,
    float* __restrict__ stats2)
{
  __shared__ float cf[64];
  coef_from_stats(stats1, g1, be1, 1.0f/(float)N_NODES, cf);

  const int n = blockIdx.x*256 + threadIdx.x;
  float acc[EMB];
#pragma unroll
  for (int c = 0; c < EMB; ++c) acc[c] = 0.f;
  if (n < N_NODES) {
#pragma unroll
    for (int c = 0; c < EMB; ++c) acc[c] = b[c];
    const float4* zp = (const float4*)(z + (size_t)n*EMB);
#pragma unroll
    for (int q8 = 0; q8 < 8; ++q8) {
      const float4 v = zp[q8];
      float mv[4] = {v.x, v.y, v.z, v.w};
#pragma unroll
      for (int j = 0; j < 4; ++j) {
        const int k = 4*q8 + j;
        const float m = fmaxf(fmaf(cf[k], mv[j], cf[EMB + k]), 0.f);
        const float* wk = w + k*EMB;
#pragma unroll
        for (int c = 0; c < EMB; ++c) acc[c] = fmaf(m, wk[c], acc[c]);
      }
    }
    float4* op = (float4*)(z + (size_t)n*EMB);
#pragma unroll
    for (int q8 = 0; q8 < 8; ++q8) {
      float4 o; o.x = acc[4*q8]; o.y = acc[4*q8+1]; o.z = acc[4*q8+2]; o.w = acc[4*q8+3];
      op[q8] = o;
    }
  }
  float ts[EMB], tss[EMB];
#pragma unroll
  for (int c = 0; c < EMB; ++c) { ts[c] = acc[c]; tss[c] = acc[c]*acc[c]; }
  block_stats_atomic(ts, tss, stats2);
}

// h += relu(bn(z2)); coef inline; then p/q for NEXT layer (if w1_next != null).
__global__ __launch_bounds__(256) void k_resid_pq(
    float* __restrict__ h, const float* __restrict__ z,
    const float* __restrict__ stats, const float* __restrict__ g, const float* __restrict__ be,
    const float* __restrict__ w1_next,
    float* __restrict__ p, float* __restrict__ q)
{
  __shared__ float cf[64];
  coef_from_stats(stats, g, be, 1.0f/(float)N_NODES, cf);

  const int n = blockIdx.x*256 + threadIdx.x;
  if (n >= N_NODES) return;
  float hn[EMB];
  const float4* zp = (const float4*)(z + (size_t)n*EMB);
  float4* hp = (float4*)(h + (size_t)n*EMB);
#pragma unroll
  for (int q8 = 0; q8 < 8; ++q8) {
    const float4 zv = zp[q8];
    const float4 hv = hp[q8];
    float mv[4] = {zv.x, zv.y, zv.z, zv.w};
    float hvv[4] = {hv.x, hv.y, hv.z, hv.w};
#pragma unroll
    for (int j = 0; j < 4; ++j) {
      const int k = 4*q8 + j;
      hn[k] = hvv[j] + fmaxf(fmaf(cf[k], mv[j], cf[EMB + k]), 0.f);
    }
    float4 o; o.x = hn[4*q8]; o.y = hn[4*q8+1]; o.z = hn[4*q8+2]; o.w = hn[4*q8+3];
    hp[q8] = o;
  }
  if (w1_next) {
    float ap[EMB], aq[EMB];
#pragma unroll
    for (int c = 0; c < EMB; ++c) { ap[c] = 0.f; aq[c] = 0.f; }
#pragma unroll
    for (int q8 = 0; q8 < 8; ++q8) {
      float4 v; v.x = hn[4*q8]; v.y = hn[4*q8+1]; v.z = hn[4*q8+2]; v.w = hn[4*q8+3];
      mac_f4(ap, v, w1_next + q8*4*EMB);
      mac_f4(aq, v, w1_next + (EMB + q8*4)*EMB);
    }
    float4* pp = (float4*)(p + (size_t)n*EMB);
    float4* qp = (float4*)(q + (size_t)n*EMB);
#pragma unroll
    for (int q8 = 0; q8 < 8; ++q8) {
      float4 o1; o1.x = ap[4*q8]; o1.y = ap[4*q8+1]; o1.z = ap[4*q8+2]; o1.w = ap[4*q8+3];
      float4 o2; o2.x = aq[4*q8]; o2.y = aq[4*q8+1]; o2.z = aq[4*q8+2]; o2.w = aq[4*q8+3];
      pp[q8] = o1; qp[q8] = o2;
    }
  }
}

// per-graph mean pool + final linear
__global__ void k_pool(const float* __restrict__ h, const int* __restrict__ batch,
                       const float* __restrict__ pw, const float* __restrict__ pb,
                       float* __restrict__ out)
{
  __shared__ float sred[256];
  __shared__ float hg[EMB];
  const int b = blockIdx.x;
  int lo = 0, hi = N_NODES;
  while (lo < hi) { int m = (lo + hi) >> 1; if (batch[m] < b) lo = m + 1; else hi = m; }
  const int start = lo;
  hi = N_NODES;
  while (lo < hi) { int m = (lo + hi) >> 1; if (batch[m] < b + 1) lo = m + 1; else hi = m; }
  const int end = lo;

  const int c = threadIdx.x & (EMB-1);
  const int r = threadIdx.x >> 5;
  float s = 0.f;
  for (int n = start + r; n < end; n += 8) s += h[(size_t)n*EMB + c];
  sred[threadIdx.x] = s;
  __syncthreads();
  if (threadIdx.x < EMB) {
    float tot = 0.f;
#pragma unroll
    for (int r2 = 0; r2 < 8; ++r2) tot += sred[r2*EMB + threadIdx.x];
    const float cnt = (float)(end - start);
    hg[threadIdx.x] = tot / fmaxf(cnt, 1.f);
  }
  __syncthreads();
  if (threadIdx.x < OUTD) {
    float acc = pb[threadIdx.x];
#pragma unroll
    for (int cc = 0; cc < EMB; ++cc) acc = fmaf(hg[cc], pw[cc*OUTD + threadIdx.x], acc);
    out[b*OUTD + threadIdx.x] = acc;
  }
}

// ---------------- host ----------------

extern "C" void kernel_launch(void* const* d_in, const int* in_sizes, int n_in,
                              void* d_out, int out_size, void* d_ws, size_t ws_size,
                              hipStream_t stream) {
  const float* x        = (const float*)d_in[0];
  const int*   ei       = (const int*)  d_in[1];
  const float* ea       = (const float*)d_in[2];
  const int*   batch    = (const int*)  d_in[3];
  const float* lin_in_w = (const float*)d_in[4];
  const float* lin_in_b = (const float*)d_in[5];
  const float* msg_w1   = (const float*)d_in[6];
  const float* msg_b1   = (const float*)d_in[7];
  const float* msg_g1   = (const float*)d_in[8];
  const float* msg_be1  = (const float*)d_in[9];
  const float* msg_w2   = (const float*)d_in[10];
  const float* msg_b2   = (const float*)d_in[11];
  const float* msg_g2   = (const float*)d_in[12];
  const float* msg_be2  = (const float*)d_in[13];
  const float* upd_w1   = (const float*)d_in[14];
  const float* upd_b1   = (const float*)d_in[15];
  const float* upd_g1   = (const float*)d_in[16];
  const float* upd_be1  = (const float*)d_in[17];
  const float* upd_w2   = (const float*)d_in[18];
  const float* upd_b2   = (const float*)d_in[19];
  const float* upd_g2   = (const float*)d_in[20];
  const float* upd_be2  = (const float*)d_in[21];
  const float* pred_w   = (const float*)d_in[22];
  const float* pred_b   = (const float*)d_in[23];
  float* out = (float*)d_out;

  // Workspace layout (~112 MB)
  char* wsb = (char*)d_ws;
  unsigned short* y = (unsigned short*)wsb;             // E*32 bf16 (y1 then y2 in place)
  float* ea_perm = (float*)(wsb + (size_t)N_EDGES*EMB*2);
  float* h       = ea_perm + (size_t)N_EDGES*ED;
  float* p       = h    + (size_t)N_NODES*EMB;
  float* q       = p    + (size_t)N_NODES*EMB;
  float* aggr    = q    + (size_t)N_NODES*EMB;          // also z1/z2 in place
  float* stats   = aggr + (size_t)N_NODES*EMB;          // 16 stages x 64 (atomic accum)
  int*   cnt     = (int*)(stats + 16*64);               // zeroed together with stats
  int*   cnt2    = cnt + N_NODES;
  int*   row_ptr = cnt2 + N_NODES;
  int*   bsum    = row_ptr + N_NODES + 1;               // 256
  int*   perm    = bsum + 256;
  int*   src_perm= perm + N_EDGES;
  int*   dst_perm= src_perm + N_EDGES;
  const size_t need = ((size_t)((char*)(dst_perm + N_EDGES) - wsb));
  if (ws_size < need) return;

  // one memset covers stats (16*64 f32) + cnt + cnt2
  hipMemsetAsync(stats, 0, (16*64 + 2*N_NODES)*sizeof(float), stream);

  k_lin_in_pq<<<NODE_GRID, 256, 0, stream>>>(x, lin_in_w, lin_in_b, msg_w1, h, p, q);
  k_hist<<<EDGE_GRID, 256, 0, stream>>>(ei, cnt);
  k_scan_a<<<NODE_GRID, 256, 0, stream>>>(cnt, row_ptr, bsum);
  k_scan_b<<<1, 256, 0, stream>>>(bsum, row_ptr);
  k_scan_c<<<NODE_GRID, 256, 0, stream>>>(row_ptr, bsum);
  k_place<<<EDGE_GRID, 256, 0, stream>>>(ei, row_ptr, cnt2, perm);
  k_permute<<<EDGE_GRID, 256, 0, stream>>>(perm, ei, ea, src_perm, dst_perm, ea_perm);

  for (int l = 0; l < NLAYERS; ++l) {
    const int st = l*4;
    const float* w1  = msg_w1 + (size_t)l*(2*EMB+ED)*EMB;
    const float* w1b = w1 + (size_t)2*EMB*EMB;  // ea rows
    const float* w2  = msg_w2 + (size_t)l*EMB*EMB;
    const float* uw1 = upd_w1 + (size_t)l*(2*EMB)*EMB;
    const float* uw2 = upd_w2 + (size_t)l*EMB*EMB;
    const float* w1_next = (l+1 < NLAYERS) ? msg_w1 + (size_t)(l+1)*(2*EMB+ED)*EMB : nullptr;

    k_msg1<<<MSG1_GRID, 256, 0, stream>>>(p, q, src_perm, dst_perm, ea_perm,
                                          w1b, msg_b1 + l*EMB, y, stats + st*64);
    k_msg2<<<MSG2_GRID, 256, 0, stream>>>(y, stats + st*64, msg_g1 + l*EMB, msg_be1 + l*EMB,
                                          w2, msg_b2 + l*EMB, stats + (st+1)*64);
    k_aggr<<<AGGR_GRID, 256, 0, stream>>>(y, row_ptr, stats + (st+1)*64,
                                          msg_g2 + l*EMB, msg_be2 + l*EMB, aggr);
    k_upd1<<<NODE_GRID, 256, 0, stream>>>(h, aggr, uw1, upd_b1 + l*EMB, stats + (st+2)*64);
    k_upd2<<<NODE_GRID, 256, 0, stream>>>(aggr, stats + (st+2)*64, upd_g1 + l*EMB, upd_be1 + l*EMB,
                                          uw2, upd_b2 + l*EMB, stats + (st+3)*64);
    k_resid_pq<<<NODE_GRID, 256, 0, stream>>>(h, aggr, stats + (st+3)*64,
                                              upd_g2 + l*EMB, upd_be2 + l*EMB, w1_next, p, q);
  }

  k_pool<<<NB, 256, 0, stream>>>(h, batch, pred_w, pred_b, out);
}

// Round 7
// 1005.318 us; speedup vs baseline: 1.8674x; 1.1533x over previous
//
#include <hip/hip_runtime.h>
#include <cstddef>

// Problem constants
#define N_NODES 50000
#define N_EDGES 800000
#define IN_DIM  128
#define EMB     32
#define ED      8
#define NLAYERS 4
#define NB      64
#define OUTD    10
#define EPS_BN  1e-5f

#define EDGE_GRID 3125   // 800000/256 exact
#define NODE_GRID 196    // ceil(50000/256)
#define AGGR_GRID 6250   // 50000/8
#define MSG1_EPT  2
#define MSG1_GRID 1563   // ceil(800000/512)
#define NT16      50000  // 800000/16
#define MSG2_TPW  16
#define MSG2_GRID 782

#define SREP 4           // stats replication (contention spread); stage stride = SREP*64

typedef short bf16x8 __attribute__((ext_vector_type(8)));
typedef float f32x4  __attribute__((ext_vector_type(4)));

// ---------------- helpers ----------------

__device__ __forceinline__ unsigned short f2bf(float x) {
  union { float f; unsigned u; } v; v.f = x;
  unsigned b = v.u + 0x7FFFu + ((v.u >> 16) & 1u);
  return (unsigned short)(b >> 16);
}
__device__ __forceinline__ float bf2f(unsigned short s) {
  union { unsigned u; float f; } v; v.u = ((unsigned)s) << 16;
  return v.f;
}

__device__ __forceinline__ void mac_f4(float acc[EMB], const float4 v, const float* __restrict__ wk) {
#pragma unroll
  for (int c = 0; c < EMB; ++c) acc[c] = fmaf(v.x, wk[c], acc[c]);
#pragma unroll
  for (int c = 0; c < EMB; ++c) acc[c] = fmaf(v.y, wk[EMB + c], acc[c]);
#pragma unroll
  for (int c = 0; c < EMB; ++c) acc[c] = fmaf(v.z, wk[2*EMB + c], acc[c]);
#pragma unroll
  for (int c = 0; c < EMB; ++c) acc[c] = fmaf(v.w, wk[3*EMB + c], acc[c]);
}

// pack 32 f32 -> bf16 row (4x uint4)
__device__ __forceinline__ void store_bf16_row(unsigned short* __restrict__ dst, const float v[EMB]) {
  unsigned u[16];
#pragma unroll
  for (int j = 0; j < 16; ++j)
    u[j] = (unsigned)f2bf(v[2*j]) | ((unsigned)f2bf(v[2*j+1]) << 16);
  uint4* dp = (uint4*)dst;
#pragma unroll
  for (int j = 0; j < 4; ++j) {
    uint4 o; o.x = u[4*j]; o.y = u[4*j+1]; o.z = u[4*j+2]; o.w = u[4*j+3];
    dp[j] = o;
  }
}

// Block reduce (sum[32], sumsq[32]) -> 64 fp32 atomicAdds into one of SREP replicated buffers.
__device__ __forceinline__ void block_stats_atomic(const float ts[EMB], const float tss[EMB],
                                                   float* __restrict__ stats_stage) {
  __shared__ float sred[256];
  const int lane = threadIdx.x & 63;
  const int wid  = threadIdx.x >> 6;
#pragma unroll
  for (int c = 0; c < EMB; ++c) {
    float a = ts[c];
    float q = tss[c];
#pragma unroll
    for (int o = 32; o > 0; o >>= 1) {
      a += __shfl_down(a, o, 64);
      q += __shfl_down(q, o, 64);
    }
    if (lane == 0) { sred[wid*64 + c] = a; sred[wid*64 + EMB + c] = q; }
  }
  __syncthreads();
  if (threadIdx.x < 64) {
    const float v = sred[threadIdx.x] + sred[64 + threadIdx.x] +
                    sred[128 + threadIdx.x] + sred[192 + threadIdx.x];
    atomicAdd(stats_stage + ((blockIdx.x & (SREP-1)) << 6) + threadIdx.x, v);
  }
}

// Inline BN-coef preamble from SREP-replicated stats: cf[c]=a, cf[32+c]=be-mu*a.
__device__ __forceinline__ void coef_from_stats(const float* __restrict__ stats_stage,
                                                const float* __restrict__ g,
                                                const float* __restrict__ be,
                                                float inv_count, float* __restrict__ cf) {
  if (threadIdx.x < EMB) {
    const int c = threadIdx.x;
    float s = 0.f, ss = 0.f;
#pragma unroll
    for (int r = 0; r < SREP; ++r) {
      s  += stats_stage[r*64 + c];
      ss += stats_stage[r*64 + EMB + c];
    }
    const float mu  = s * inv_count;
    const float var = ss * inv_count - mu*mu;
    const float a = g[c] * rsqrtf(var + EPS_BN);
    cf[c] = a;
    cf[EMB + c] = fmaf(-mu, a, be[c]);
  }
  __syncthreads();
}

// ---------------- kernels ----------------

// h = x @ lin_in_w + lin_in_b ; then p/q (bf16, b1 folded into p) for layer 0.
__global__ __launch_bounds__(256) void k_lin_in_pq(
    const float* __restrict__ x, const float* __restrict__ w, const float* __restrict__ b,
    const float* __restrict__ w1, const float* __restrict__ b1,
    float* __restrict__ h, unsigned short* __restrict__ p, unsigned short* __restrict__ q)
{
  const int n = blockIdx.x*256 + threadIdx.x;
  if (n >= N_NODES) return;
  float acc[EMB];
#pragma unroll
  for (int c = 0; c < EMB; ++c) acc[c] = b[c];
  const float4* xp = (const float4*)(x + (size_t)n*IN_DIM);
#pragma unroll 4
  for (int q8 = 0; q8 < IN_DIM/4; ++q8) mac_f4(acc, xp[q8], w + q8*4*EMB);
  float4* hp = (float4*)(h + (size_t)n*EMB);
#pragma unroll
  for (int q8 = 0; q8 < 8; ++q8) {
    float4 o; o.x = acc[4*q8]; o.y = acc[4*q8+1]; o.z = acc[4*q8+2]; o.w = acc[4*q8+3];
    hp[q8] = o;
  }
  float ap[EMB], aq[EMB];
#pragma unroll
  for (int c = 0; c < EMB; ++c) { ap[c] = b1[c]; aq[c] = 0.f; }
#pragma unroll
  for (int q8 = 0; q8 < 8; ++q8) {
    float4 v; v.x = acc[4*q8]; v.y = acc[4*q8+1]; v.z = acc[4*q8+2]; v.w = acc[4*q8+3];
    mac_f4(ap, v, w1 + q8*4*EMB);
    mac_f4(aq, v, w1 + (EMB + q8*4)*EMB);
  }
  store_bf16_row(p + (size_t)n*EMB, ap);
  store_bf16_row(q + (size_t)n*EMB, aq);
}

// ---- CSR build ----
__global__ __launch_bounds__(256) void k_hist(const int* __restrict__ ei, int* __restrict__ cnt) {
  const int e = blockIdx.x*256 + threadIdx.x;
  if (e < N_EDGES) atomicAdd(&cnt[ei[N_EDGES + e]], 1);
}

__global__ __launch_bounds__(256) void k_scan_a(const int* __restrict__ cnt,
                                                int* __restrict__ row_ptr, int* __restrict__ bsum) {
  __shared__ int s[256];
  const int gid = blockIdx.x*256 + threadIdx.x;
  const int v = (gid < N_NODES) ? cnt[gid] : 0;
  s[threadIdx.x] = v;
  __syncthreads();
  for (int o = 1; o < 256; o <<= 1) {
    const int t = (threadIdx.x >= o) ? s[threadIdx.x - o] : 0;
    __syncthreads();
    s[threadIdx.x] += t;
    __syncthreads();
  }
  if (gid < N_NODES) row_ptr[gid] = s[threadIdx.x] - v;
  if (threadIdx.x == 255) bsum[blockIdx.x] = s[255];
}

__global__ __launch_bounds__(256) void k_scan_b(int* __restrict__ bsum, int* __restrict__ row_ptr) {
  __shared__ int s[256];
  const int v = (threadIdx.x < NODE_GRID) ? bsum[threadIdx.x] : 0;
  s[threadIdx.x] = v;
  __syncthreads();
  for (int o = 1; o < 256; o <<= 1) {
    const int t = (threadIdx.x >= o) ? s[threadIdx.x - o] : 0;
    __syncthreads();
    s[threadIdx.x] += t;
    __syncthreads();
  }
  if (threadIdx.x < NODE_GRID) bsum[threadIdx.x] = s[threadIdx.x] - v;
  if (threadIdx.x == 0) row_ptr[N_NODES] = N_EDGES;
}

__global__ __launch_bounds__(256) void k_scan_c(int* __restrict__ row_ptr, const int* __restrict__ bsum) {
  const int gid = blockIdx.x*256 + threadIdx.x;
  if (gid < N_NODES) row_ptr[gid] += bsum[blockIdx.x];
}

__global__ __launch_bounds__(256) void k_place(const int* __restrict__ ei,
                                               const int* __restrict__ row_ptr,
                                               int* __restrict__ cnt2, int* __restrict__ perm) {
  const int e = blockIdx.x*256 + threadIdx.x;
  if (e >= N_EDGES) return;
  const int d = ei[N_EDGES + e];
  const int pos = row_ptr[d] + atomicAdd(&cnt2[d], 1);
  perm[pos] = e;
}

// Gather edge data into CSR position order; ea stored bf16 (16B/edge).
__global__ __launch_bounds__(256) void k_permute(
    const int* __restrict__ perm, const int* __restrict__ ei, const float* __restrict__ ea,
    int* __restrict__ src_perm, int* __restrict__ dst_perm, unsigned short* __restrict__ ea_perm)
{
  const int i = blockIdx.x*256 + threadIdx.x;
  const int e = perm[i];
  src_perm[i] = ei[e];
  dst_perm[i] = ei[N_EDGES + e];
  const float4* src4 = (const float4*)(ea + (size_t)e*ED);
  const float4 v0 = src4[0], v1 = src4[1];
  const float ev[8] = {v0.x, v0.y, v0.z, v0.w, v1.x, v1.y, v1.z, v1.w};
  unsigned u[4];
#pragma unroll
  for (int j = 0; j < 4; ++j)
    u[j] = (unsigned)f2bf(ev[2*j]) | ((unsigned)f2bf(ev[2*j+1]) << 16);
  uint4 o; o.x = u[0]; o.y = u[1]; o.z = u[2]; o.w = u[3];
  *(uint4*)(ea_perm + (size_t)i*ED) = o;
}

// y1[i] = p[dst] + q[src] + ea[i]@w1b (b1 folded in p); bf16 inputs; store bf16 [E][32]; stats.
__global__ __launch_bounds__(256) void k_msg1(
    const unsigned short* __restrict__ pb, const unsigned short* __restrict__ qb,
    const int* __restrict__ src_perm, const int* __restrict__ dst_perm,
    const unsigned short* __restrict__ ea_perm,
    const float* __restrict__ w1b,
    unsigned short* __restrict__ y, float* __restrict__ stats)
{
  float ts[EMB], tss[EMB];
#pragma unroll
  for (int c = 0; c < EMB; ++c) { ts[c] = 0.f; tss[c] = 0.f; }
  const int base = blockIdx.x*(256*MSG1_EPT) + threadIdx.x;
  for (int it = 0; it < MSG1_EPT; ++it) {
    const int i = base + it*256;
    if (i >= N_EDGES) break;
    const int dst = dst_perm[i];
    const int src = src_perm[i];
    float acc[EMB];
    const uint4* pd = (const uint4*)(pb + (size_t)dst*EMB);
    const uint4* qs = (const uint4*)(qb + (size_t)src*EMB);
#pragma unroll
    for (int j4 = 0; j4 < 4; ++j4) {
      const uint4 a = pd[j4];
      const uint4 b = qs[j4];
      const unsigned ua[4] = {a.x, a.y, a.z, a.w};
      const unsigned ub[4] = {b.x, b.y, b.z, b.w};
#pragma unroll
      for (int t = 0; t < 4; ++t) {
        acc[j4*8 + 2*t]   = bf2f((unsigned short)(ua[t] & 0xFFFFu)) +
                            bf2f((unsigned short)(ub[t] & 0xFFFFu));
        acc[j4*8 + 2*t+1] = bf2f((unsigned short)(ua[t] >> 16)) +
                            bf2f((unsigned short)(ub[t] >> 16));
      }
    }
    const uint4 eraw = *(const uint4*)(ea_perm + (size_t)i*ED);
    const unsigned ue[4] = {eraw.x, eraw.y, eraw.z, eraw.w};
    float ev[8];
#pragma unroll
    for (int t = 0; t < 4; ++t) {
      ev[2*t]   = bf2f((unsigned short)(ue[t] & 0xFFFFu));
      ev[2*t+1] = bf2f((unsigned short)(ue[t] >> 16));
    }
#pragma unroll
    for (int k = 0; k < 8; ++k) {
      const float* wk = w1b + k*EMB;
#pragma unroll
      for (int c = 0; c < EMB; ++c) acc[c] = fmaf(ev[k], wk[c], acc[c]);
    }

    unsigned short us[EMB];
#pragma unroll
    for (int c = 0; c < EMB; ++c) us[c] = f2bf(acc[c]);
    unsigned u[16];
#pragma unroll
    for (int j = 0; j < 16; ++j)
      u[j] = (unsigned)us[2*j] | ((unsigned)us[2*j+1] << 16);
    uint4* dp = (uint4*)(y + (size_t)i*EMB);
#pragma unroll
    for (int j = 0; j < 4; ++j) {
      uint4 o; o.x = u[4*j]; o.y = u[4*j+1]; o.z = u[4*j+2]; o.w = u[4*j+3];
      dp[j] = o;
    }
#pragma unroll
    for (int c = 0; c < EMB; ++c) {
      const float v = bf2f(us[c]);
      ts[c] += v;
      tss[c] = fmaf(v, v, tss[c]);
    }
  }
  block_stats_atomic(ts, tss, stats);
}

// MFMA msg2: y2 = bf16( relu(bn1(y1)) @ bf16(W2) + b2 ), in place on y; coef inline; stats.
__global__ __launch_bounds__(256) void k_msg2(
    unsigned short* __restrict__ y,
    const float* __restrict__ stats1, const float* __restrict__ g1, const float* __restrict__ be1,
    const float* __restrict__ w2, const float* __restrict__ b2,
    float* __restrict__ stats2)
{
  __shared__ __align__(16) unsigned short lds_t[4][16*32];
  __shared__ float lds_s[4][32], lds_q[4][32];
  __shared__ float cf[64];

  coef_from_stats(stats1, g1, be1, 1.0f/(float)N_EDGES, cf);

  const int lane = threadIdx.x & 63;
  const int wid  = threadIdx.x >> 6;
  const int n0 = lane & 15;
  const int kb = lane >> 4;   // 0..3

  bf16x8 Blo, Bhi;
#pragma unroll
  for (int j = 0; j < 8; ++j) {
    Blo[j] = (short)f2bf(w2[(kb*8 + j)*EMB + n0]);
    Bhi[j] = (short)f2bf(w2[(kb*8 + j)*EMB + 16 + n0]);
  }
  float a1[8], c1[8];
#pragma unroll
  for (int j = 0; j < 8; ++j) {
    a1[j] = cf[kb*8 + j];
    c1[j] = cf[EMB + kb*8 + j];
  }
  const float b2c0 = b2[n0], b2c1 = b2[16 + n0];

  float ts[8], tss[8];
#pragma unroll
  for (int j = 0; j < 8; ++j) { ts[j] = 0.f; tss[j] = 0.f; }

  const int tile0 = blockIdx.x * (MSG2_TPW*4);
  for (int t = 0; t < MSG2_TPW; ++t) {
    const int tile = tile0 + t*4 + wid;
    if (tile >= NT16) break;
    const size_t e0 = (size_t)tile * 16;

    const uint4 araw = *(const uint4*)(y + (e0 + n0)*EMB + kb*8);
    unsigned int ua[4] = {araw.x, araw.y, araw.z, araw.w};
    bf16x8 A;
#pragma unroll
    for (int j = 0; j < 4; ++j) {
      float v0 = bf2f((unsigned short)(ua[j] & 0xFFFFu));
      float v1 = bf2f((unsigned short)(ua[j] >> 16));
      v0 = fmaxf(fmaf(a1[2*j],   v0, c1[2*j]),   0.f);
      v1 = fmaxf(fmaf(a1[2*j+1], v1, c1[2*j+1]), 0.f);
      A[2*j]   = (short)f2bf(v0);
      A[2*j+1] = (short)f2bf(v1);
    }

    f32x4 acc0 = {0.f, 0.f, 0.f, 0.f};
    f32x4 acc1 = {0.f, 0.f, 0.f, 0.f};
    acc0 = __builtin_amdgcn_mfma_f32_16x16x32_bf16(A, Blo, acc0, 0, 0, 0);
    acc1 = __builtin_amdgcn_mfma_f32_16x16x32_bf16(A, Bhi, acc1, 0, 0, 0);

#pragma unroll
    for (int r = 0; r < 4; ++r) {
      const int row = kb*4 + r;
      lds_t[wid][row*32 + n0]      = f2bf(acc0[r] + b2c0);
      lds_t[wid][row*32 + 16 + n0] = f2bf(acc1[r] + b2c1);
    }
    const uint4 orow = *(const uint4*)&lds_t[wid][(lane>>2)*32 + (lane&3)*8];
    *(uint4*)(y + (e0 + (lane>>2))*EMB + (lane&3)*8) = orow;

    unsigned int uo[4] = {orow.x, orow.y, orow.z, orow.w};
#pragma unroll
    for (int j = 0; j < 4; ++j) {
      const float v0 = bf2f((unsigned short)(uo[j] & 0xFFFFu));
      const float v1 = bf2f((unsigned short)(uo[j] >> 16));
      ts[2*j]   += v0;  tss[2*j]   = fmaf(v0, v0, tss[2*j]);
      ts[2*j+1] += v1;  tss[2*j+1] = fmaf(v1, v1, tss[2*j+1]);
    }
  }

#pragma unroll
  for (int j = 0; j < 8; ++j) {
    float s = ts[j], qq = tss[j];
#pragma unroll
    for (int o = 4; o < 64; o <<= 1) {
      s  += __shfl_xor(s, o, 64);
      qq += __shfl_xor(qq, o, 64);
    }
    ts[j] = s; tss[j] = qq;
  }
  if (lane < 4) {
#pragma unroll
    for (int j = 0; j < 8; ++j) {
      lds_s[wid][lane*8 + j] = ts[j];
      lds_q[wid][lane*8 + j] = tss[j];
    }
  }
  __syncthreads();
  if (threadIdx.x < 64) {
    const int c = threadIdx.x & 31;
    const int kind = threadIdx.x >> 5;
    float v = 0.f;
#pragma unroll
    for (int wq = 0; wq < 4; ++wq)
      v += kind ? lds_q[wq][c] : lds_s[wq][c];
    atomicAdd(stats2 + ((blockIdx.x & (SREP-1)) << 6) + kind*32 + c, v);
  }
}

// CSR gather, sequential, 2 cols/lane + 2 rows/iter; coef inline.
__global__ __launch_bounds__(256) void k_aggr(
    const unsigned short* __restrict__ y, const int* __restrict__ row_ptr,
    const float* __restrict__ stats2, const float* __restrict__ g2, const float* __restrict__ be2,
    float* __restrict__ aggr)
{
  __shared__ float cf[64];
  coef_from_stats(stats2, g2, be2, 1.0f/(float)N_EDGES, cf);

  const int grp = threadIdx.x >> 5;  // 0..7
  const int l   = threadIdx.x & 31;
  const int rof = l >> 4;            // 0..1 row offset
  const int cp  = l & 15;            // column pair
  const int n = blockIdx.x*8 + grp;
  if (n >= N_NODES) return;
  const float a0 = cf[2*cp],     b0 = cf[EMB + 2*cp];
  const float a1 = cf[2*cp + 1], b1 = cf[EMB + 2*cp + 1];
  const int lo = row_ptr[n], hi = row_ptr[n+1];
  float s0 = 0.f, s1 = 0.f;
  for (int i = lo + rof; i < hi; i += 2) {
    const unsigned u = *(const unsigned*)(y + (size_t)i*EMB + 2*cp);
    const float v0 = bf2f((unsigned short)(u & 0xFFFFu));
    const float v1 = bf2f((unsigned short)(u >> 16));
    s0 += fmaxf(fmaf(a0, v0, b0), 0.f);
    s1 += fmaxf(fmaf(a1, v1, b1), 0.f);
  }
  s0 += __shfl_xor(s0, 16, 64);
  s1 += __shfl_xor(s1, 16, 64);
  if (rof == 0) {
    float2 o; o.x = s0; o.y = s1;
    *(float2*)(aggr + (size_t)n*EMB + 2*cp) = o;
  }
}

// z1 = concat(h, aggr) @ uw1 + b, IN PLACE into aggr. stats.
__global__ __launch_bounds__(256) void k_upd1(
    const float* __restrict__ h, float* __restrict__ aggr,
    const float* __restrict__ w, const float* __restrict__ b,
    float* __restrict__ stats)
{
  const int n = blockIdx.x*256 + threadIdx.x;
  float acc[EMB];
#pragma unroll
  for (int c = 0; c < EMB; ++c) acc[c] = 0.f;
  if (n < N_NODES) {
#pragma unroll
    for (int c = 0; c < EMB; ++c) acc[c] = b[c];
    const float4* hp = (const float4*)(h + (size_t)n*EMB);
    const float4* ap = (const float4*)(aggr + (size_t)n*EMB);
#pragma unroll
    for (int q8 = 0; q8 < 8; ++q8) mac_f4(acc, hp[q8], w + q8*4*EMB);
#pragma unroll
    for (int q8 = 0; q8 < 8; ++q8) mac_f4(acc, ap[q8], w + (EMB + q8*4)*EMB);
    float4* zp = (float4*)(aggr + (size_t)n*EMB);
#pragma unroll
    for (int q8 = 0; q8 < 8; ++q8) {
      float4 o; o.x = acc[4*q8]; o.y = acc[4*q8+1]; o.z = acc[4*q8+2]; o.w = acc[4*q8+3];
      zp[q8] = o;
    }
  }
  float ts[EMB], tss[EMB];
#pragma unroll
  for (int c = 0; c < EMB; ++c) { ts[c] = acc[c]; tss[c] = acc[c]*acc[c]; }
  block_stats_atomic(ts, tss, stats);
}

// z2 = relu(bn(z1)) @ uw2 + b, in place; coef inline; stats.
__global__ __launch_bounds__(256) void k_upd2(
    float* __restrict__ z,
    const float* __restrict__ stats1, const float* __restrict__ g1, const float* __restrict__ be1,
    const float* __restrict__ w, const float* __restrict__ b,
    float* __restrict__ stats2)
{
  __shared__ float cf[64];
  coef_from_stats(stats1, g1, be1, 1.0f/(float)N_NODES, cf);

  const int n = blockIdx.x*256 + threadIdx.x;
  float acc[EMB];
#pragma unroll
  for (int c = 0; c < EMB; ++c) acc[c] = 0.f;
  if (n < N_NODES) {
#pragma unroll
    for (int c = 0; c < EMB; ++c) acc[c] = b[c];
    const float4* zp = (const float4*)(z + (size_t)n*EMB);
#pragma unroll
    for (int q8 = 0; q8 < 8; ++q8) {
      const float4 v = zp[q8];
      float mv[4] = {v.x, v.y, v.z, v.w};
#pragma unroll
      for (int j = 0; j < 4; ++j) {
        const int k = 4*q8 + j;
        const float m = fmaxf(fmaf(cf[k], mv[j], cf[EMB + k]), 0.f);
        const float* wk = w + k*EMB;
#pragma unroll
        for (int c = 0; c < EMB; ++c) acc[c] = fmaf(m, wk[c], acc[c]);
      }
    }
    float4* op = (float4*)(z + (size_t)n*EMB);
#pragma unroll
    for (int q8 = 0; q8 < 8; ++q8) {
      float4 o; o.x = acc[4*q8]; o.y = acc[4*q8+1]; o.z = acc[4*q8+2]; o.w = acc[4*q8+3];
      op[q8] = o;
    }
  }
  float ts[EMB], tss[EMB];
#pragma unroll
  for (int c = 0; c < EMB; ++c) { ts[c] = acc[c]; tss[c] = acc[c]*acc[c]; }
  block_stats_atomic(ts, tss, stats2);
}

// h += relu(bn(z2)); then p/q (bf16, b1_next folded into p) for NEXT layer.
__global__ __launch_bounds__(256) void k_resid_pq(
    float* __restrict__ h, const float* __restrict__ z,
    const float* __restrict__ stats, const float* __restrict__ g, const float* __restrict__ be,
    const float* __restrict__ w1_next, const float* __restrict__ b1_next,
    unsigned short* __restrict__ p, unsigned short* __restrict__ q)
{
  __shared__ float cf[64];
  coef_from_stats(stats, g, be, 1.0f/(float)N_NODES, cf);

  const int n = blockIdx.x*256 + threadIdx.x;
  if (n >= N_NODES) return;
  float hn[EMB];
  const float4* zp = (const float4*)(z + (size_t)n*EMB);
  float4* hp = (float4*)(h + (size_t)n*EMB);
#pragma unroll
  for (int q8 = 0; q8 < 8; ++q8) {
    const float4 zv = zp[q8];
    const float4 hv = hp[q8];
    float mv[4] = {zv.x, zv.y, zv.z, zv.w};
    float hvv[4] = {hv.x, hv.y, hv.z, hv.w};
#pragma unroll
    for (int j = 0; j < 4; ++j) {
      const int k = 4*q8 + j;
      hn[k] = hvv[j] + fmaxf(fmaf(cf[k], mv[j], cf[EMB + k]), 0.f);
    }
    float4 o; o.x = hn[4*q8]; o.y = hn[4*q8+1]; o.z = hn[4*q8+2]; o.w = hn[4*q8+3];
    hp[q8] = o;
  }
  if (w1_next) {
    float ap[EMB], aq[EMB];
#pragma unroll
    for (int c = 0; c < EMB; ++c) { ap[c] = b1_next[c]; aq[c] = 0.f; }
#pragma unroll
    for (int q8 = 0; q8 < 8; ++q8) {
      float4 v; v.x = hn[4*q8]; v.y = hn[4*q8+1]; v.z = hn[4*q8+2]; v.w = hn[4*q8+3];
      mac_f4(ap, v, w1_next + q8*4*EMB);
      mac_f4(aq, v, w1_next + (EMB + q8*4)*EMB);
    }
    store_bf16_row(p + (size_t)n*EMB, ap);
    store_bf16_row(q + (size_t)n*EMB, aq);
  }
}

// per-graph mean pool + final linear
__global__ void k_pool(const float* __restrict__ h, const int* __restrict__ batch,
                       const float* __restrict__ pw, const float* __restrict__ pb,
                       float* __restrict__ out)
{
  __shared__ float sred[256];
  __shared__ float hg[EMB];
  const int b = blockIdx.x;
  int lo = 0, hi = N_NODES;
  while (lo < hi) { int m = (lo + hi) >> 1; if (batch[m] < b) lo = m + 1; else hi = m; }
  const int start = lo;
  hi = N_NODES;
  while (lo < hi) { int m = (lo + hi) >> 1; if (batch[m] < b + 1) lo = m + 1; else hi = m; }
  const int end = lo;

  const int c = threadIdx.x & (EMB-1);
  const int r = threadIdx.x >> 5;
  float s = 0.f;
  for (int n = start + r; n < end; n += 8) s += h[(size_t)n*EMB + c];
  sred[threadIdx.x] = s;
  __syncthreads();
  if (threadIdx.x < EMB) {
    float tot = 0.f;
#pragma unroll
    for (int r2 = 0; r2 < 8; ++r2) tot += sred[r2*EMB + threadIdx.x];
    const float cnt = (float)(end - start);
    hg[threadIdx.x] = tot / fmaxf(cnt, 1.f);
  }
  __syncthreads();
  if (threadIdx.x < OUTD) {
    float acc = pb[threadIdx.x];
#pragma unroll
    for (int cc = 0; cc < EMB; ++cc) acc = fmaf(hg[cc], pw[cc*OUTD + threadIdx.x], acc);
    out[b*OUTD + threadIdx.x] = acc;
  }
}

// ---------------- host ----------------

extern "C" void kernel_launch(void* const* d_in, const int* in_sizes, int n_in,
                              void* d_out, int out_size, void* d_ws, size_t ws_size,
                              hipStream_t stream) {
  const float* x        = (const float*)d_in[0];
  const int*   ei       = (const int*)  d_in[1];
  const float* ea       = (const float*)d_in[2];
  const int*   batch    = (const int*)  d_in[3];
  const float* lin_in_w = (const float*)d_in[4];
  const float* lin_in_b = (const float*)d_in[5];
  const float* msg_w1   = (const float*)d_in[6];
  const float* msg_b1   = (const float*)d_in[7];
  const float* msg_g1   = (const float*)d_in[8];
  const float* msg_be1  = (const float*)d_in[9];
  const float* msg_w2   = (const float*)d_in[10];
  const float* msg_b2   = (const float*)d_in[11];
  const float* msg_g2   = (const float*)d_in[12];
  const float* msg_be2  = (const float*)d_in[13];
  const float* upd_w1   = (const float*)d_in[14];
  const float* upd_b1   = (const float*)d_in[15];
  const float* upd_g1   = (const float*)d_in[16];
  const float* upd_be1  = (const float*)d_in[17];
  const float* upd_w2   = (const float*)d_in[18];
  const float* upd_b2   = (const float*)d_in[19];
  const float* upd_g2   = (const float*)d_in[20];
  const float* upd_be2  = (const float*)d_in[21];
  const float* pred_w   = (const float*)d_in[22];
  const float* pred_b   = (const float*)d_in[23];
  float* out = (float*)d_out;

  // Workspace layout (~94 MB)
  char* wsb = (char*)d_ws;
  unsigned short* y  = (unsigned short*)wsb;                      // E*32 bf16 = 51.2 MB
  unsigned short* eap= (unsigned short*)(wsb + (size_t)N_EDGES*EMB*2);  // E*8 bf16 = 12.8 MB
  unsigned short* p  = eap + (size_t)N_EDGES*ED;                  // N*32 bf16
  unsigned short* q  = p + (size_t)N_NODES*EMB;                   // N*32 bf16
  float* h       = (float*)(q + (size_t)N_NODES*EMB);             // N*32 f32
  float* aggr    = h + (size_t)N_NODES*EMB;                       // N*32 f32 (z1/z2 in place)
  float* stats   = aggr + (size_t)N_NODES*EMB;                    // 16 stages x SREP x 64
  int*   cnt     = (int*)(stats + 16*SREP*64);
  int*   cnt2    = cnt + N_NODES;
  int*   row_ptr = cnt2 + N_NODES;
  int*   bsum    = row_ptr + N_NODES + 1;
  int*   perm    = bsum + 256;
  int*   src_perm= perm + N_EDGES;
  int*   dst_perm= src_perm + N_EDGES;
  const size_t need = ((size_t)((char*)(dst_perm + N_EDGES) - wsb));
  if (ws_size < need) return;

  // one memset covers stats + cnt + cnt2
  hipMemsetAsync(stats, 0, (16*SREP*64 + 2*N_NODES)*sizeof(float), stream);

  k_lin_in_pq<<<NODE_GRID, 256, 0, stream>>>(x, lin_in_w, lin_in_b, msg_w1, msg_b1, h, p, q);
  k_hist<<<EDGE_GRID, 256, 0, stream>>>(ei, cnt);
  k_scan_a<<<NODE_GRID, 256, 0, stream>>>(cnt, row_ptr, bsum);
  k_scan_b<<<1, 256, 0, stream>>>(bsum, row_ptr);
  k_scan_c<<<NODE_GRID, 256, 0, stream>>>(row_ptr, bsum);
  k_place<<<EDGE_GRID, 256, 0, stream>>>(ei, row_ptr, cnt2, perm);
  k_permute<<<EDGE_GRID, 256, 0, stream>>>(perm, ei, ea, src_perm, dst_perm, eap);

  for (int l = 0; l < NLAYERS; ++l) {
    const int st = l*4;
    const float* w1  = msg_w1 + (size_t)l*(2*EMB+ED)*EMB;
    const float* w1b = w1 + (size_t)2*EMB*EMB;  // ea rows
    const float* w2  = msg_w2 + (size_t)l*EMB*EMB;
    const float* uw1 = upd_w1 + (size_t)l*(2*EMB)*EMB;
    const float* uw2 = upd_w2 + (size_t)l*EMB*EMB;
    const float* w1_next = (l+1 < NLAYERS) ? msg_w1 + (size_t)(l+1)*(2*EMB+ED)*EMB : nullptr;
    const float* b1_next = (l+1 < NLAYERS) ? msg_b1 + (size_t)(l+1)*EMB : nullptr;

    k_msg1<<<MSG1_GRID, 256, 0, stream>>>(p, q, src_perm, dst_perm, eap,
                                          w1b, y, stats + (size_t)st*SREP*64);
    k_msg2<<<MSG2_GRID, 256, 0, stream>>>(y, stats + (size_t)st*SREP*64,
                                          msg_g1 + l*EMB, msg_be1 + l*EMB,
                                          w2, msg_b2 + l*EMB, stats + (size_t)(st+1)*SREP*64);
    k_aggr<<<AGGR_GRID, 256, 0, stream>>>(y, row_ptr, stats + (size_t)(st+1)*SREP*64,
                                          msg_g2 + l*EMB, msg_be2 + l*EMB, aggr);
    k_upd1<<<NODE_GRID, 256, 0, stream>>>(h, aggr, uw1, upd_b1 + l*EMB,
                                          stats + (size_t)(st+2)*SREP*64);
    k_upd2<<<NODE_GRID, 256, 0, stream>>>(aggr, stats + (size_t)(st+2)*SREP*64,
                                          upd_g1 + l*EMB, upd_be1 + l*EMB,
                                          uw2, upd_b2 + l*EMB, stats + (size_t)(st+3)*SREP*64);
    k_resid_pq<<<NODE_GRID, 256, 0, stream>>>(h, aggr, stats + (size_t)(st+3)*SREP*64,
                                              upd_g2 + l*EMB, upd_be2 + l*EMB,
                                              w1_next, b1_next, p, q);
  }

  k_pool<<<NB, 256, 0, stream>>>(h, batch, pred_w, pred_b, out);
}

// Round 8
// 951.724 us; speedup vs baseline: 1.9725x; 1.0563x over previous
//
#include <hip/hip_runtime.h>
#include <cstddef>

// Problem constants
#define N_NODES 50000
#define N_EDGES 800000
#define IN_DIM  128
#define EMB     32
#define ED      8
#define NLAYERS 4
#define NB      64
#define OUTD    10
#define EPS_BN  1e-5f

#define EDGE_GRID 3125   // 800000/256 exact
#define NODE_GRID 196    // ceil(50000/256)  (scan kernels)
#define NODE4_GRID 782   // ceil(50000/64)   (4-wave node kernels)
#define AGGR_GRID 6250   // 50000/8
#define MSG1_EPT  2
#define MSG1_GRID 1563   // ceil(800000/512)
#define NT16      50000  // 800000/16
#define MSG2_TPW  16
#define MSG2_GRID 782

#define SREP 4           // stats replication; stage stride = SREP*64

typedef short bf16x8 __attribute__((ext_vector_type(8)));
typedef float f32x4  __attribute__((ext_vector_type(4)));

// ---------------- helpers ----------------

__device__ __forceinline__ unsigned short f2bf(float x) {
  union { float f; unsigned u; } v; v.f = x;
  unsigned b = v.u + 0x7FFFu + ((v.u >> 16) & 1u);
  return (unsigned short)(b >> 16);
}
__device__ __forceinline__ float bf2f(unsigned short s) {
  union { unsigned u; float f; } v; v.u = ((unsigned)s) << 16;
  return v.f;
}

__device__ __forceinline__ uint4 pack8_bf16(const float v[8]) {
  uint4 o;
  o.x = (unsigned)f2bf(v[0]) | ((unsigned)f2bf(v[1]) << 16);
  o.y = (unsigned)f2bf(v[2]) | ((unsigned)f2bf(v[3]) << 16);
  o.z = (unsigned)f2bf(v[4]) | ((unsigned)f2bf(v[5]) << 16);
  o.w = (unsigned)f2bf(v[6]) | ((unsigned)f2bf(v[7]) << 16);
  return o;
}

// acc8[j] += v.{x,y,z,w} * wk[t*EMB + j], wk wave-uniform (col-range per wave)
__device__ __forceinline__ void mac8_f4(float acc[8], const float4 v, const float* __restrict__ wk) {
#pragma unroll
  for (int j = 0; j < 8; ++j) acc[j] = fmaf(v.x, wk[j], acc[j]);
#pragma unroll
  for (int j = 0; j < 8; ++j) acc[j] = fmaf(v.y, wk[EMB + j], acc[j]);
#pragma unroll
  for (int j = 0; j < 8; ++j) acc[j] = fmaf(v.z, wk[2*EMB + j], acc[j]);
#pragma unroll
  for (int j = 0; j < 8; ++j) acc[j] = fmaf(v.w, wk[3*EMB + j], acc[j]);
}

// Inline BN-coef preamble from SREP-replicated stats: cf[c]=a, cf[32+c]=be-mu*a.
__device__ __forceinline__ void coef_from_stats(const float* __restrict__ stats_stage,
                                                const float* __restrict__ g,
                                                const float* __restrict__ be,
                                                float inv_count, float* __restrict__ cf) {
  if (threadIdx.x < EMB) {
    const int c = threadIdx.x;
    float s = 0.f, ss = 0.f;
#pragma unroll
    for (int r = 0; r < SREP; ++r) {
      s  += stats_stage[r*64 + c];
      ss += stats_stage[r*64 + EMB + c];
    }
    const float mu  = s * inv_count;
    const float var = ss * inv_count - mu*mu;
    const float a = g[c] * rsqrtf(var + EPS_BN);
    cf[c] = a;
    cf[EMB + c] = fmaf(-mu, a, be[c]);
  }
  __syncthreads();
}

// Per-wave stats (8 cols each) -> LDS -> 64 atomics. Call with ts/tss as this
// thread's per-node values; barrier inside separates producers' reads from
// callers' subsequent in-place writes.
__device__ __forceinline__ void wave_stats_atomic(float ts[8], float tss[8],
                                                  float* __restrict__ lds_s,
                                                  float* __restrict__ lds_q,
                                                  float* __restrict__ stats_stage) {
  const int lane = threadIdx.x & 63;
  const int wv   = threadIdx.x >> 6;
#pragma unroll
  for (int j = 0; j < 8; ++j) {
    float a = ts[j], b = tss[j];
#pragma unroll
    for (int o = 32; o > 0; o >>= 1) {
      a += __shfl_down(a, o, 64);
      b += __shfl_down(b, o, 64);
    }
    ts[j] = a; tss[j] = b;
  }
  if (lane == 0) {
#pragma unroll
    for (int j = 0; j < 8; ++j) {
      lds_s[wv*8 + j] = ts[j];
      lds_q[wv*8 + j] = tss[j];
    }
  }
  __syncthreads();
  if (threadIdx.x < 64) {
    const float v = (threadIdx.x < 32) ? lds_s[threadIdx.x] : lds_q[threadIdx.x - 32];
    atomicAdd(stats_stage + ((blockIdx.x & (SREP-1)) << 6) + threadIdx.x, v);
  }
}

// mixed reduce for msg kernels (unchanged structure, 256-thread shuffle+LDS)
__device__ __forceinline__ void block_stats_atomic(const float ts[EMB], const float tss[EMB],
                                                   float* __restrict__ stats_stage) {
  __shared__ float sred[256];
  const int lane = threadIdx.x & 63;
  const int wid  = threadIdx.x >> 6;
#pragma unroll
  for (int c = 0; c < EMB; ++c) {
    float a = ts[c];
    float q = tss[c];
#pragma unroll
    for (int o = 32; o > 0; o >>= 1) {
      a += __shfl_down(a, o, 64);
      q += __shfl_down(q, o, 64);
    }
    if (lane == 0) { sred[wid*64 + c] = a; sred[wid*64 + EMB + c] = q; }
  }
  __syncthreads();
  if (threadIdx.x < 64) {
    const float v = sred[threadIdx.x] + sred[64 + threadIdx.x] +
                    sred[128 + threadIdx.x] + sred[192 + threadIdx.x];
    atomicAdd(stats_stage + ((blockIdx.x & (SREP-1)) << 6) + threadIdx.x, v);
  }
}

// ---------------- node kernels (4-wave col-split: wave w -> cols 8w..8w+7, lane = node) ----------------

// h = x @ lin_in_w + lin_in_b ; p/q (bf16, b1 folded into p) via LDS h-exchange.
__global__ __launch_bounds__(256) void k_lin_in_pq(
    const float* __restrict__ x, const float* __restrict__ w, const float* __restrict__ b,
    const float* __restrict__ w1, const float* __restrict__ b1,
    float* __restrict__ h, unsigned short* __restrict__ p, unsigned short* __restrict__ q)
{
  __shared__ float lds_h[64][33];
  const int lane = threadIdx.x & 63;
  const int wv   = threadIdx.x >> 6;
  const int n  = blockIdx.x*64 + lane;
  const int c0 = wv*8;
  if (n < N_NODES) {
    float acc[8];
#pragma unroll
    for (int j = 0; j < 8; ++j) acc[j] = b[c0 + j];
    const float4* xp = (const float4*)(x + (size_t)n*IN_DIM);
#pragma unroll 8
    for (int k4 = 0; k4 < IN_DIM/4; ++k4)
      mac8_f4(acc, xp[k4], w + (k4*4)*EMB + c0);
    float4 o0, o1;
    o0.x = acc[0]; o0.y = acc[1]; o0.z = acc[2]; o0.w = acc[3];
    o1.x = acc[4]; o1.y = acc[5]; o1.z = acc[6]; o1.w = acc[7];
    *(float4*)(h + (size_t)n*EMB + c0)     = o0;
    *(float4*)(h + (size_t)n*EMB + c0 + 4) = o1;
#pragma unroll
    for (int j = 0; j < 8; ++j) lds_h[lane][c0 + j] = acc[j];
  }
  __syncthreads();
  if (n < N_NODES) {
    float ap[8], aq[8];
#pragma unroll
    for (int j = 0; j < 8; ++j) { ap[j] = b1[c0 + j]; aq[j] = 0.f; }
#pragma unroll
    for (int k = 0; k < EMB; ++k) {
      const float hv = lds_h[lane][k];
      const float* wp = w1 + k*EMB + c0;
      const float* wq = w1 + (EMB + k)*EMB + c0;
#pragma unroll
      for (int j = 0; j < 8; ++j) ap[j] = fmaf(hv, wp[j], ap[j]);
#pragma unroll
      for (int j = 0; j < 8; ++j) aq[j] = fmaf(hv, wq[j], aq[j]);
    }
    *(uint4*)(p + (size_t)n*EMB + c0) = pack8_bf16(ap);
    *(uint4*)(q + (size_t)n*EMB + c0) = pack8_bf16(aq);
  }
}

// z1 = concat(h, aggr) @ uw1 + b, IN PLACE into aggr (write after barrier). stats.
__global__ __launch_bounds__(256) void k_upd1(
    const float* __restrict__ h, float* __restrict__ aggr,
    const float* __restrict__ w, const float* __restrict__ b,
    float* __restrict__ stats)
{
  __shared__ float lds_s[32], lds_q[32];
  const int lane = threadIdx.x & 63;
  const int wv   = threadIdx.x >> 6;
  const int n  = blockIdx.x*64 + lane;
  const int c0 = wv*8;
  float acc[8];
#pragma unroll
  for (int j = 0; j < 8; ++j) acc[j] = 0.f;
  if (n < N_NODES) {
#pragma unroll
    for (int j = 0; j < 8; ++j) acc[j] = b[c0 + j];
    const float4* hp = (const float4*)(h + (size_t)n*EMB);
    const float4* ap = (const float4*)(aggr + (size_t)n*EMB);
#pragma unroll
    for (int k4 = 0; k4 < 8; ++k4) mac8_f4(acc, hp[k4], w + (k4*4)*EMB + c0);
#pragma unroll
    for (int k4 = 0; k4 < 8; ++k4) mac8_f4(acc, ap[k4], w + (EMB + k4*4)*EMB + c0);
  }
  float ts[8], tss[8];
#pragma unroll
  for (int j = 0; j < 8; ++j) { ts[j] = acc[j]; tss[j] = acc[j]*acc[j]; }
  wave_stats_atomic(ts, tss, lds_s, lds_q, stats);  // barrier inside
  if (n < N_NODES) {
    float4 o0, o1;
    o0.x = acc[0]; o0.y = acc[1]; o0.z = acc[2]; o0.w = acc[3];
    o1.x = acc[4]; o1.y = acc[5]; o1.z = acc[6]; o1.w = acc[7];
    *(float4*)(aggr + (size_t)n*EMB + c0)     = o0;
    *(float4*)(aggr + (size_t)n*EMB + c0 + 4) = o1;
  }
}

// z2 = relu(bn(z1)) @ uw2 + b, in place; coef inline; stats.
__global__ __launch_bounds__(256) void k_upd2(
    float* __restrict__ z,
    const float* __restrict__ stats1, const float* __restrict__ g1, const float* __restrict__ be1,
    const float* __restrict__ w, const float* __restrict__ b,
    float* __restrict__ stats2)
{
  __shared__ float cf[64];
  __shared__ float lds_s[32], lds_q[32];
  coef_from_stats(stats1, g1, be1, 1.0f/(float)N_NODES, cf);

  const int lane = threadIdx.x & 63;
  const int wv   = threadIdx.x >> 6;
  const int n  = blockIdx.x*64 + lane;
  const int c0 = wv*8;
  float acc[8];
#pragma unroll
  for (int j = 0; j < 8; ++j) acc[j] = 0.f;
  if (n < N_NODES) {
#pragma unroll
    for (int j = 0; j < 8; ++j) acc[j] = b[c0 + j];
    const float4* zp = (const float4*)(z + (size_t)n*EMB);
#pragma unroll
    for (int k4 = 0; k4 < 8; ++k4) {
      const float4 v = zp[k4];
      const float mv[4] = {v.x, v.y, v.z, v.w};
#pragma unroll
      for (int t = 0; t < 4; ++t) {
        const int k = 4*k4 + t;
        const float m = fmaxf(fmaf(cf[k], mv[t], cf[EMB + k]), 0.f);
        const float* wk = w + k*EMB + c0;
#pragma unroll
        for (int j = 0; j < 8; ++j) acc[j] = fmaf(m, wk[j], acc[j]);
      }
    }
  }
  float ts[8], tss[8];
#pragma unroll
  for (int j = 0; j < 8; ++j) { ts[j] = acc[j]; tss[j] = acc[j]*acc[j]; }
  wave_stats_atomic(ts, tss, lds_s, lds_q, stats2);  // barrier inside
  if (n < N_NODES) {
    float4 o0, o1;
    o0.x = acc[0]; o0.y = acc[1]; o0.z = acc[2]; o0.w = acc[3];
    o1.x = acc[4]; o1.y = acc[5]; o1.z = acc[6]; o1.w = acc[7];
    *(float4*)(z + (size_t)n*EMB + c0)     = o0;
    *(float4*)(z + (size_t)n*EMB + c0 + 4) = o1;
  }
}

// h += relu(bn(z2)); p/q (bf16, b1_next folded into p) via LDS hn-exchange.
__global__ __launch_bounds__(256) void k_resid_pq(
    float* __restrict__ h, const float* __restrict__ z,
    const float* __restrict__ stats, const float* __restrict__ g, const float* __restrict__ be,
    const float* __restrict__ w1_next, const float* __restrict__ b1_next,
    unsigned short* __restrict__ p, unsigned short* __restrict__ q)
{
  __shared__ float cf[64];
  __shared__ float lds_h[64][33];
  coef_from_stats(stats, g, be, 1.0f/(float)N_NODES, cf);

  const int lane = threadIdx.x & 63;
  const int wv   = threadIdx.x >> 6;
  const int n  = blockIdx.x*64 + lane;
  const int c0 = wv*8;
  if (n < N_NODES) {
    const float4* zp = (const float4*)(z + (size_t)n*EMB + c0);
    float4* hp = (float4*)(h + (size_t)n*EMB + c0);
    float hn[8];
    const float4 z0 = zp[0], z1 = zp[1];
    const float4 h0 = hp[0], h1 = hp[1];
    const float zv[8] = {z0.x, z0.y, z0.z, z0.w, z1.x, z1.y, z1.z, z1.w};
    const float hv[8] = {h0.x, h0.y, h0.z, h0.w, h1.x, h1.y, h1.z, h1.w};
#pragma unroll
    for (int j = 0; j < 8; ++j) {
      const int k = c0 + j;
      hn[j] = hv[j] + fmaxf(fmaf(cf[k], zv[j], cf[EMB + k]), 0.f);
      lds_h[lane][k] = hn[j];
    }
    float4 o0, o1;
    o0.x = hn[0]; o0.y = hn[1]; o0.z = hn[2]; o0.w = hn[3];
    o1.x = hn[4]; o1.y = hn[5]; o1.z = hn[6]; o1.w = hn[7];
    hp[0] = o0; hp[1] = o1;
  }
  __syncthreads();
  if (n < N_NODES && w1_next) {
    float ap[8], aq[8];
#pragma unroll
    for (int j = 0; j < 8; ++j) { ap[j] = b1_next[c0 + j]; aq[j] = 0.f; }
#pragma unroll
    for (int k = 0; k < EMB; ++k) {
      const float hvv = lds_h[lane][k];
      const float* wp = w1_next + k*EMB + c0;
      const float* wq = w1_next + (EMB + k)*EMB + c0;
#pragma unroll
      for (int j = 0; j < 8; ++j) ap[j] = fmaf(hvv, wp[j], ap[j]);
#pragma unroll
      for (int j = 0; j < 8; ++j) aq[j] = fmaf(hvv, wq[j], aq[j]);
    }
    *(uint4*)(p + (size_t)n*EMB + c0) = pack8_bf16(ap);
    *(uint4*)(q + (size_t)n*EMB + c0) = pack8_bf16(aq);
  }
}

// ---------------- CSR build ----------------
__global__ __launch_bounds__(256) void k_hist(const int* __restrict__ ei, int* __restrict__ cnt) {
  const int e = blockIdx.x*256 + threadIdx.x;
  if (e < N_EDGES) atomicAdd(&cnt[ei[N_EDGES + e]], 1);
}

__global__ __launch_bounds__(256) void k_scan_a(const int* __restrict__ cnt,
                                                int* __restrict__ row_ptr, int* __restrict__ bsum) {
  __shared__ int s[256];
  const int gid = blockIdx.x*256 + threadIdx.x;
  const int v = (gid < N_NODES) ? cnt[gid] : 0;
  s[threadIdx.x] = v;
  __syncthreads();
  for (int o = 1; o < 256; o <<= 1) {
    const int t = (threadIdx.x >= o) ? s[threadIdx.x - o] : 0;
    __syncthreads();
    s[threadIdx.x] += t;
    __syncthreads();
  }
  if (gid < N_NODES) row_ptr[gid] = s[threadIdx.x] - v;
  if (threadIdx.x == 255) bsum[blockIdx.x] = s[255];
}

__global__ __launch_bounds__(256) void k_scan_b(int* __restrict__ bsum, int* __restrict__ row_ptr) {
  __shared__ int s[256];
  const int v = (threadIdx.x < NODE_GRID) ? bsum[threadIdx.x] : 0;
  s[threadIdx.x] = v;
  __syncthreads();
  for (int o = 1; o < 256; o <<= 1) {
    const int t = (threadIdx.x >= o) ? s[threadIdx.x - o] : 0;
    __syncthreads();
    s[threadIdx.x] += t;
    __syncthreads();
  }
  if (threadIdx.x < NODE_GRID) bsum[threadIdx.x] = s[threadIdx.x] - v;
  if (threadIdx.x == 0) row_ptr[N_NODES] = N_EDGES;
}

__global__ __launch_bounds__(256) void k_scan_c(int* __restrict__ row_ptr, const int* __restrict__ bsum) {
  const int gid = blockIdx.x*256 + threadIdx.x;
  if (gid < N_NODES) row_ptr[gid] += bsum[blockIdx.x];
}

__global__ __launch_bounds__(256) void k_place(const int* __restrict__ ei,
                                               const int* __restrict__ row_ptr,
                                               int* __restrict__ cnt2, int* __restrict__ perm) {
  const int e = blockIdx.x*256 + threadIdx.x;
  if (e >= N_EDGES) return;
  const int d = ei[N_EDGES + e];
  const int pos = row_ptr[d] + atomicAdd(&cnt2[d], 1);
  perm[pos] = e;
}

__global__ __launch_bounds__(256) void k_permute(
    const int* __restrict__ perm, const int* __restrict__ ei, const float* __restrict__ ea,
    int* __restrict__ src_perm, int* __restrict__ dst_perm, unsigned short* __restrict__ ea_perm)
{
  const int i = blockIdx.x*256 + threadIdx.x;
  const int e = perm[i];
  src_perm[i] = ei[e];
  dst_perm[i] = ei[N_EDGES + e];
  const float4* src4 = (const float4*)(ea + (size_t)e*ED);
  const float4 v0 = src4[0], v1 = src4[1];
  const float ev[8] = {v0.x, v0.y, v0.z, v0.w, v1.x, v1.y, v1.z, v1.w};
  unsigned u[4];
#pragma unroll
  for (int j = 0; j < 4; ++j)
    u[j] = (unsigned)f2bf(ev[2*j]) | ((unsigned)f2bf(ev[2*j+1]) << 16);
  uint4 o; o.x = u[0]; o.y = u[1]; o.z = u[2]; o.w = u[3];
  *(uint4*)(ea_perm + (size_t)i*ED) = o;
}

// ---------------- edge kernels ----------------

// y1[i] = p[dst] + q[src] + ea[i]@w1b (b1 folded in p); bf16 in/out; stats.
__global__ __launch_bounds__(256) void k_msg1(
    const unsigned short* __restrict__ pb, const unsigned short* __restrict__ qb,
    const int* __restrict__ src_perm, const int* __restrict__ dst_perm,
    const unsigned short* __restrict__ ea_perm,
    const float* __restrict__ w1b,
    unsigned short* __restrict__ y, float* __restrict__ stats)
{
  float ts[EMB], tss[EMB];
#pragma unroll
  for (int c = 0; c < EMB; ++c) { ts[c] = 0.f; tss[c] = 0.f; }
  const int base = blockIdx.x*(256*MSG1_EPT) + threadIdx.x;
  for (int it = 0; it < MSG1_EPT; ++it) {
    const int i = base + it*256;
    if (i >= N_EDGES) break;
    const int dst = dst_perm[i];
    const int src = src_perm[i];
    float acc[EMB];
    const uint4* pd = (const uint4*)(pb + (size_t)dst*EMB);
    const uint4* qs = (const uint4*)(qb + (size_t)src*EMB);
#pragma unroll
    for (int j4 = 0; j4 < 4; ++j4) {
      const uint4 a = pd[j4];
      const uint4 b = qs[j4];
      const unsigned ua[4] = {a.x, a.y, a.z, a.w};
      const unsigned ub[4] = {b.x, b.y, b.z, b.w};
#pragma unroll
      for (int t = 0; t < 4; ++t) {
        acc[j4*8 + 2*t]   = bf2f((unsigned short)(ua[t] & 0xFFFFu)) +
                            bf2f((unsigned short)(ub[t] & 0xFFFFu));
        acc[j4*8 + 2*t+1] = bf2f((unsigned short)(ua[t] >> 16)) +
                            bf2f((unsigned short)(ub[t] >> 16));
      }
    }
    const uint4 eraw = *(const uint4*)(ea_perm + (size_t)i*ED);
    const unsigned ue[4] = {eraw.x, eraw.y, eraw.z, eraw.w};
    float ev[8];
#pragma unroll
    for (int t = 0; t < 4; ++t) {
      ev[2*t]   = bf2f((unsigned short)(ue[t] & 0xFFFFu));
      ev[2*t+1] = bf2f((unsigned short)(ue[t] >> 16));
    }
#pragma unroll
    for (int k = 0; k < 8; ++k) {
      const float* wk = w1b + k*EMB;
#pragma unroll
      for (int c = 0; c < EMB; ++c) acc[c] = fmaf(ev[k], wk[c], acc[c]);
    }

    unsigned short us[EMB];
#pragma unroll
    for (int c = 0; c < EMB; ++c) us[c] = f2bf(acc[c]);
    unsigned u[16];
#pragma unroll
    for (int j = 0; j < 16; ++j)
      u[j] = (unsigned)us[2*j] | ((unsigned)us[2*j+1] << 16);
    uint4* dp = (uint4*)(y + (size_t)i*EMB);
#pragma unroll
    for (int j = 0; j < 4; ++j) {
      uint4 o; o.x = u[4*j]; o.y = u[4*j+1]; o.z = u[4*j+2]; o.w = u[4*j+3];
      dp[j] = o;
    }
#pragma unroll
    for (int c = 0; c < EMB; ++c) {
      const float v = bf2f(us[c]);
      ts[c] += v;
      tss[c] = fmaf(v, v, tss[c]);
    }
  }
  block_stats_atomic(ts, tss, stats);
}

// MFMA msg2: y2 = bf16( relu(bn1(y1)) @ bf16(W2) + b2 ), in place on y; coef inline; stats.
__global__ __launch_bounds__(256) void k_msg2(
    unsigned short* __restrict__ y,
    const float* __restrict__ stats1, const float* __restrict__ g1, const float* __restrict__ be1,
    const float* __restrict__ w2, const float* __restrict__ b2,
    float* __restrict__ stats2)
{
  __shared__ __align__(16) unsigned short lds_t[4][16*32];
  __shared__ float lds_s[4][32], lds_q[4][32];
  __shared__ float cf[64];

  coef_from_stats(stats1, g1, be1, 1.0f/(float)N_EDGES, cf);

  const int lane = threadIdx.x & 63;
  const int wid  = threadIdx.x >> 6;
  const int n0 = lane & 15;
  const int kb = lane >> 4;   // 0..3

  bf16x8 Blo, Bhi;
#pragma unroll
  for (int j = 0; j < 8; ++j) {
    Blo[j] = (short)f2bf(w2[(kb*8 + j)*EMB + n0]);
    Bhi[j] = (short)f2bf(w2[(kb*8 + j)*EMB + 16 + n0]);
  }
  float a1[8], c1[8];
#pragma unroll
  for (int j = 0; j < 8; ++j) {
    a1[j] = cf[kb*8 + j];
    c1[j] = cf[EMB + kb*8 + j];
  }
  const float b2c0 = b2[n0], b2c1 = b2[16 + n0];

  float ts[8], tss[8];
#pragma unroll
  for (int j = 0; j < 8; ++j) { ts[j] = 0.f; tss[j] = 0.f; }

  const int tile0 = blockIdx.x * (MSG2_TPW*4);
  for (int t = 0; t < MSG2_TPW; ++t) {
    const int tile = tile0 + t*4 + wid;
    if (tile >= NT16) break;
    const size_t e0 = (size_t)tile * 16;

    const uint4 araw = *(const uint4*)(y + (e0 + n0)*EMB + kb*8);
    unsigned int ua[4] = {araw.x, araw.y, araw.z, araw.w};
    bf16x8 A;
#pragma unroll
    for (int j = 0; j < 4; ++j) {
      float v0 = bf2f((unsigned short)(ua[j] & 0xFFFFu));
      float v1 = bf2f((unsigned short)(ua[j] >> 16));
      v0 = fmaxf(fmaf(a1[2*j],   v0, c1[2*j]),   0.f);
      v1 = fmaxf(fmaf(a1[2*j+1], v1, c1[2*j+1]), 0.f);
      A[2*j]   = (short)f2bf(v0);
      A[2*j+1] = (short)f2bf(v1);
    }

    f32x4 acc0 = {0.f, 0.f, 0.f, 0.f};
    f32x4 acc1 = {0.f, 0.f, 0.f, 0.f};
    acc0 = __builtin_amdgcn_mfma_f32_16x16x32_bf16(A, Blo, acc0, 0, 0, 0);
    acc1 = __builtin_amdgcn_mfma_f32_16x16x32_bf16(A, Bhi, acc1, 0, 0, 0);

#pragma unroll
    for (int r = 0; r < 4; ++r) {
      const int row = kb*4 + r;
      lds_t[wid][row*32 + n0]      = f2bf(acc0[r] + b2c0);
      lds_t[wid][row*32 + 16 + n0] = f2bf(acc1[r] + b2c1);
    }
    const uint4 orow = *(const uint4*)&lds_t[wid][(lane>>2)*32 + (lane&3)*8];
    *(uint4*)(y + (e0 + (lane>>2))*EMB + (lane&3)*8) = orow;

    unsigned int uo[4] = {orow.x, orow.y, orow.z, orow.w};
#pragma unroll
    for (int j = 0; j < 4; ++j) {
      const float v0 = bf2f((unsigned short)(uo[j] & 0xFFFFu));
      const float v1 = bf2f((unsigned short)(uo[j] >> 16));
      ts[2*j]   += v0;  tss[2*j]   = fmaf(v0, v0, tss[2*j]);
      ts[2*j+1] += v1;  tss[2*j+1] = fmaf(v1, v1, tss[2*j+1]);
    }
  }

#pragma unroll
  for (int j = 0; j < 8; ++j) {
    float s = ts[j], qq = tss[j];
#pragma unroll
    for (int o = 4; o < 64; o <<= 1) {
      s  += __shfl_xor(s, o, 64);
      qq += __shfl_xor(qq, o, 64);
    }
    ts[j] = s; tss[j] = qq;
  }
  if (lane < 4) {
#pragma unroll
    for (int j = 0; j < 8; ++j) {
      lds_s[wid][lane*8 + j] = ts[j];
      lds_q[wid][lane*8 + j] = tss[j];
    }
  }
  __syncthreads();
  if (threadIdx.x < 64) {
    const int c = threadIdx.x & 31;
    const int kind = threadIdx.x >> 5;
    float v = 0.f;
#pragma unroll
    for (int wq = 0; wq < 4; ++wq)
      v += kind ? lds_q[wq][c] : lds_s[wq][c];
    atomicAdd(stats2 + ((blockIdx.x & (SREP-1)) << 6) + kind*32 + c, v);
  }
}

// CSR gather, sequential, 2 cols/lane + 2 rows/iter; coef inline.
__global__ __launch_bounds__(256) void k_aggr(
    const unsigned short* __restrict__ y, const int* __restrict__ row_ptr,
    const float* __restrict__ stats2, const float* __restrict__ g2, const float* __restrict__ be2,
    float* __restrict__ aggr)
{
  __shared__ float cf[64];
  coef_from_stats(stats2, g2, be2, 1.0f/(float)N_EDGES, cf);

  const int grp = threadIdx.x >> 5;
  const int l   = threadIdx.x & 31;
  const int rof = l >> 4;
  const int cp  = l & 15;
  const int n = blockIdx.x*8 + grp;
  if (n >= N_NODES) return;
  const float a0 = cf[2*cp],     b0 = cf[EMB + 2*cp];
  const float a1 = cf[2*cp + 1], b1 = cf[EMB + 2*cp + 1];
  const int lo = row_ptr[n], hi = row_ptr[n+1];
  float s0 = 0.f, s1 = 0.f;
  for (int i = lo + rof; i < hi; i += 2) {
    const unsigned u = *(const unsigned*)(y + (size_t)i*EMB + 2*cp);
    const float v0 = bf2f((unsigned short)(u & 0xFFFFu));
    const float v1 = bf2f((unsigned short)(u >> 16));
    s0 += fmaxf(fmaf(a0, v0, b0), 0.f);
    s1 += fmaxf(fmaf(a1, v1, b1), 0.f);
  }
  s0 += __shfl_xor(s0, 16, 64);
  s1 += __shfl_xor(s1, 16, 64);
  if (rof == 0) {
    float2 o; o.x = s0; o.y = s1;
    *(float2*)(aggr + (size_t)n*EMB + 2*cp) = o;
  }
}

// per-graph mean pool + final linear
__global__ void k_pool(const float* __restrict__ h, const int* __restrict__ batch,
                       const float* __restrict__ pw, const float* __restrict__ pb,
                       float* __restrict__ out)
{
  __shared__ float sred[256];
  __shared__ float hg[EMB];
  const int b = blockIdx.x;
  int lo = 0, hi = N_NODES;
  while (lo < hi) { int m = (lo + hi) >> 1; if (batch[m] < b) lo = m + 1; else hi = m; }
  const int start = lo;
  hi = N_NODES;
  while (lo < hi) { int m = (lo + hi) >> 1; if (batch[m] < b + 1) lo = m + 1; else hi = m; }
  const int end = lo;

  const int c = threadIdx.x & (EMB-1);
  const int r = threadIdx.x >> 5;
  float s = 0.f;
  for (int n = start + r; n < end; n += 8) s += h[(size_t)n*EMB + c];
  sred[threadIdx.x] = s;
  __syncthreads();
  if (threadIdx.x < EMB) {
    float tot = 0.f;
#pragma unroll
    for (int r2 = 0; r2 < 8; ++r2) tot += sred[r2*EMB + threadIdx.x];
    const float cnt = (float)(end - start);
    hg[threadIdx.x] = tot / fmaxf(cnt, 1.f);
  }
  __syncthreads();
  if (threadIdx.x < OUTD) {
    float acc = pb[threadIdx.x];
#pragma unroll
    for (int cc = 0; cc < EMB; ++cc) acc = fmaf(hg[cc], pw[cc*OUTD + threadIdx.x], acc);
    out[b*OUTD + threadIdx.x] = acc;
  }
}

// ---------------- host ----------------

extern "C" void kernel_launch(void* const* d_in, const int* in_sizes, int n_in,
                              void* d_out, int out_size, void* d_ws, size_t ws_size,
                              hipStream_t stream) {
  const float* x        = (const float*)d_in[0];
  const int*   ei       = (const int*)  d_in[1];
  const float* ea       = (const float*)d_in[2];
  const int*   batch    = (const int*)  d_in[3];
  const float* lin_in_w = (const float*)d_in[4];
  const float* lin_in_b = (const float*)d_in[5];
  const float* msg_w1   = (const float*)d_in[6];
  const float* msg_b1   = (const float*)d_in[7];
  const float* msg_g1   = (const float*)d_in[8];
  const float* msg_be1  = (const float*)d_in[9];
  const float* msg_w2   = (const float*)d_in[10];
  const float* msg_b2   = (const float*)d_in[11];
  const float* msg_g2   = (const float*)d_in[12];
  const float* msg_be2  = (const float*)d_in[13];
  const float* upd_w1   = (const float*)d_in[14];
  const float* upd_b1   = (const float*)d_in[15];
  const float* upd_g1   = (const float*)d_in[16];
  const float* upd_be1  = (const float*)d_in[17];
  const float* upd_w2   = (const float*)d_in[18];
  const float* upd_b2   = (const float*)d_in[19];
  const float* upd_g2   = (const float*)d_in[20];
  const float* upd_be2  = (const float*)d_in[21];
  const float* pred_w   = (const float*)d_in[22];
  const float* pred_b   = (const float*)d_in[23];
  float* out = (float*)d_out;

  // Workspace layout (~94 MB)
  char* wsb = (char*)d_ws;
  unsigned short* y  = (unsigned short*)wsb;                      // E*32 bf16 = 51.2 MB
  unsigned short* eap= (unsigned short*)(wsb + (size_t)N_EDGES*EMB*2);  // E*8 bf16 = 12.8 MB
  unsigned short* p  = eap + (size_t)N_EDGES*ED;                  // N*32 bf16
  unsigned short* q  = p + (size_t)N_NODES*EMB;                   // N*32 bf16
  float* h       = (float*)(q + (size_t)N_NODES*EMB);             // N*32 f32
  float* aggr    = h + (size_t)N_NODES*EMB;                       // N*32 f32 (z1/z2 in place)
  float* stats   = aggr + (size_t)N_NODES*EMB;                    // 16 stages x SREP x 64
  int*   cnt     = (int*)(stats + 16*SREP*64);
  int*   cnt2    = cnt + N_NODES;
  int*   row_ptr = cnt2 + N_NODES;
  int*   bsum    = row_ptr + N_NODES + 1;
  int*   perm    = bsum + 256;
  int*   src_perm= perm + N_EDGES;
  int*   dst_perm= src_perm + N_EDGES;
  const size_t need = ((size_t)((char*)(dst_perm + N_EDGES) - wsb));
  if (ws_size < need) return;

  hipMemsetAsync(stats, 0, (16*SREP*64 + 2*N_NODES)*sizeof(float), stream);

  k_lin_in_pq<<<NODE4_GRID, 256, 0, stream>>>(x, lin_in_w, lin_in_b, msg_w1, msg_b1, h, p, q);
  k_hist<<<EDGE_GRID, 256, 0, stream>>>(ei, cnt);
  k_scan_a<<<NODE_GRID, 256, 0, stream>>>(cnt, row_ptr, bsum);
  k_scan_b<<<1, 256, 0, stream>>>(bsum, row_ptr);
  k_scan_c<<<NODE_GRID, 256, 0, stream>>>(row_ptr, bsum);
  k_place<<<EDGE_GRID, 256, 0, stream>>>(ei, row_ptr, cnt2, perm);
  k_permute<<<EDGE_GRID, 256, 0, stream>>>(perm, ei, ea, src_perm, dst_perm, eap);

  for (int l = 0; l < NLAYERS; ++l) {
    const int st = l*4;
    const float* w1  = msg_w1 + (size_t)l*(2*EMB+ED)*EMB;
    const float* w1b = w1 + (size_t)2*EMB*EMB;
    const float* w2  = msg_w2 + (size_t)l*EMB*EMB;
    const float* uw1 = upd_w1 + (size_t)l*(2*EMB)*EMB;
    const float* uw2 = upd_w2 + (size_t)l*EMB*EMB;
    const float* w1_next = (l+1 < NLAYERS) ? msg_w1 + (size_t)(l+1)*(2*EMB+ED)*EMB : nullptr;
    const float* b1_next = (l+1 < NLAYERS) ? msg_b1 + (size_t)(l+1)*EMB : nullptr;

    k_msg1<<<MSG1_GRID, 256, 0, stream>>>(p, q, src_perm, dst_perm, eap,
                                          w1b, y, stats + (size_t)st*SREP*64);
    k_msg2<<<MSG2_GRID, 256, 0, stream>>>(y, stats + (size_t)st*SREP*64,
                                          msg_g1 + l*EMB, msg_be1 + l*EMB,
                                          w2, msg_b2 + l*EMB, stats + (size_t)(st+1)*SREP*64);
    k_aggr<<<AGGR_GRID, 256, 0, stream>>>(y, row_ptr, stats + (size_t)(st+1)*SREP*64,
                                          msg_g2 + l*EMB, msg_be2 + l*EMB, aggr);
    k_upd1<<<NODE4_GRID, 256, 0, stream>>>(h, aggr, uw1, upd_b1 + l*EMB,
                                           stats + (size_t)(st+2)*SREP*64);
    k_upd2<<<NODE4_GRID, 256, 0, stream>>>(aggr, stats + (size_t)(st+2)*SREP*64,
                                           upd_g1 + l*EMB, upd_be1 + l*EMB,
                                           uw2, upd_b2 + l*EMB, stats + (size_t)(st+3)*SREP*64);
    k_resid_pq<<<NODE4_GRID, 256, 0, stream>>>(h, aggr, stats + (size_t)(st+3)*SREP*64,
                                               upd_g2 + l*EMB, upd_be2 + l*EMB,
                                               w1_next, b1_next, p, q);
  }

  k_pool<<<NB, 256, 0, stream>>>(h, batch, pred_w, pred_b, out);
}